// Round 1
// baseline (780.033 us; speedup 1.0000x reference)
//
#include <hip/hip_runtime.h>
#include <hip/hip_bf16.h>

#define D128 128
#define NEG_SLOPE 0.2f

// ---------------------------------------------------------------------------
// CSR build
// ---------------------------------------------------------------------------
__global__ void zero_int_kernel(int* __restrict__ p, int n) {
    int i = blockIdx.x * blockDim.x + threadIdx.x;
    if (i < n) p[i] = 0;
}

__global__ void count_kernel(const int* __restrict__ dst, int E, int* __restrict__ cnt) {
    int e = blockIdx.x * blockDim.x + threadIdx.x;
    if (e < E) atomicAdd(&cnt[dst[e]], 1);
}

// single-block exclusive scan over cnt[0..N) -> off[0..N], also writes cursor copy
__global__ void scan_kernel(const int* __restrict__ cnt, int* __restrict__ off,
                            int* __restrict__ cur, int N) {
    __shared__ int buf[1024];
    __shared__ int carry;
    int t = threadIdx.x;
    if (t == 0) carry = 0;
    __syncthreads();
    for (int base = 0; base < N; base += 1024) {
        int v = (base + t < N) ? cnt[base + t] : 0;
        buf[t] = v;
        __syncthreads();
        for (int s = 1; s < 1024; s <<= 1) {
            int add = (t >= s) ? buf[t - s] : 0;
            __syncthreads();
            buf[t] += add;
            __syncthreads();
        }
        int inc = buf[t];
        int exc = inc - v;
        int c = carry;
        if (base + t < N) { off[base + t] = c + exc; cur[base + t] = c + exc; }
        int tot = buf[1023];
        __syncthreads();
        if (t == 0) carry = c + tot;
        __syncthreads();
    }
    if (t == 0) off[N] = carry;
}

__global__ void fill_kernel(const int* __restrict__ src, const int* __restrict__ dst, int E,
                            int* __restrict__ cur, int* __restrict__ csr_src) {
    int e = blockIdx.x * blockDim.x + threadIdx.x;
    if (e < E) {
        int p = atomicAdd(&cur[dst[e]], 1);
        csr_src[p] = src[e];
    }
}

// ---------------------------------------------------------------------------
// fp32 GEMM: Y[N,128] = X[N,128] @ W[128,128].  64 rows x 128 cols per block.
// 256 threads, each computes 8 rows x 4 cols.
// ---------------------------------------------------------------------------
__global__ __launch_bounds__(256) void gemm128_kernel(const float* __restrict__ X,
                                                      const float* __restrict__ W,
                                                      float* __restrict__ Y, int N) {
    __shared__ float xs[64][128];
    const int t = threadIdx.x;
    const int row0 = blockIdx.x * 64;

    // stage X tile (float4, coalesced)
    for (int i = t; i < 64 * 128 / 4; i += 256) {
        int elem = i * 4;
        int r = elem / 128, c = elem % 128;
        int gr = row0 + r;
        float4 v = make_float4(0.f, 0.f, 0.f, 0.f);
        if (gr < N) v = *(const float4*)&X[(size_t)gr * 128 + c];
        *(float4*)&xs[r][c] = v;
    }
    __syncthreads();

    const int c0 = (t & 31) * 4;
    const int r0 = (t >> 5) * 8;
    float acc[8][4];
#pragma unroll
    for (int r = 0; r < 8; ++r)
#pragma unroll
        for (int j = 0; j < 4; ++j) acc[r][j] = 0.f;

    for (int k = 0; k < 128; ++k) {
        float4 w = *(const float4*)&W[k * 128 + c0];
#pragma unroll
        for (int r = 0; r < 8; ++r) {
            float xv = xs[r0 + r][k];
            acc[r][0] += xv * w.x;
            acc[r][1] += xv * w.y;
            acc[r][2] += xv * w.z;
            acc[r][3] += xv * w.w;
        }
    }
#pragma unroll
    for (int r = 0; r < 8; ++r) {
        int gr = row0 + r0 + r;
        if (gr < N)
            *(float4*)&Y[(size_t)gr * 128 + c0] =
                make_float4(acc[r][0], acc[r][1], acc[r][2], acc[r][3]);
    }
}

// ---------------------------------------------------------------------------
// attention scalars: a_s[n,h] = sum_c h[n,h*C+c]*att_s[h*C+c]  (same for a_d)
// one node per 128-thread block
// ---------------------------------------------------------------------------
template <int H, int C>
__global__ __launch_bounds__(128) void att_kernel(const float* __restrict__ hbuf,
                                                  const float* __restrict__ att_s,
                                                  const float* __restrict__ att_d,
                                                  float* __restrict__ a_s,
                                                  float* __restrict__ a_d, int N) {
    __shared__ float r1[128], r2[128];
    int n = blockIdx.x;
    int t = threadIdx.x;
    float hv = hbuf[(size_t)n * 128 + t];
    r1[t] = hv * att_s[t];
    r2[t] = hv * att_d[t];
    __syncthreads();
    for (int s = C / 2; s > 0; s >>= 1) {
        if ((t & (C - 1)) < s) {
            r1[t] += r1[t + s];
            r2[t] += r2[t + s];
        }
        __syncthreads();
    }
    if ((t & (C - 1)) == 0) {
        a_s[(size_t)n * H + t / C] = r1[t];
        a_d[(size_t)n * H + t / C] = r2[t];
    }
}

// ---------------------------------------------------------------------------
// aggregation + bias + ELU + residual + LayerNorm.  One node per 128-thr block.
// ---------------------------------------------------------------------------
template <int H, int C, bool RES>
__global__ __launch_bounds__(128) void agg_kernel(const float* __restrict__ hbuf,
                                                  const float* __restrict__ a_s,
                                                  const float* __restrict__ a_d,
                                                  const int* __restrict__ off,
                                                  const int* __restrict__ csr_src,
                                                  const float* __restrict__ xprev,
                                                  const float* __restrict__ bias,
                                                  const float* __restrict__ ln_g,
                                                  const float* __restrict__ ln_b,
                                                  float* __restrict__ xout) {
    const int n = blockIdx.x;
    const int t = threadIdx.x;          // 0..127
    const int hh = t / C;               // head of this channel
    const int base = off[n];
    const int deg = off[n + 1] - base;

    __shared__ float adn[H];
    __shared__ float mS[H], sS[H];
    __shared__ float red[128];
    __shared__ int ssrc[64];
    __shared__ float ev[64 * H];

    if (t < H) adn[t] = a_d[(size_t)n * H + t];
    __syncthreads();

    // ---- pass A: per-head max of leaky_relu(a_s[src]+a_d[n]) -------------
    // thread t handles (e,h) pairs idx = t, t+128, ...; h = idx % H is constant
    float pm = -1e30f;
    for (int idx = t; idx < deg * H; idx += 128) {
        int e = idx / H, h = idx % H;
        int s = csr_src[base + e];
        float lg = a_s[(size_t)s * H + h] + adn[h];
        lg = lg >= 0.f ? lg : NEG_SLOPE * lg;
        pm = fmaxf(pm, lg);
    }
    red[t] = pm;
    __syncthreads();
    for (int s = 64; s >= H; s >>= 1) {
        if (t < s) red[t] = fmaxf(red[t], red[t + s]);
        __syncthreads();
    }
    if (t < H) mS[t] = red[t];
    __syncthreads();

    // ---- pass B: per-head sum of exp(logit - m) --------------------------
    float ps = 0.f;
    for (int idx = t; idx < deg * H; idx += 128) {
        int e = idx / H, h = idx % H;
        int s = csr_src[base + e];
        float lg = a_s[(size_t)s * H + h] + adn[h];
        lg = lg >= 0.f ? lg : NEG_SLOPE * lg;
        ps += expf(lg - mS[h]);
    }
    red[t] = ps;
    __syncthreads();
    for (int s = 64; s >= H; s >>= 1) {
        if (t < s) red[t] += red[t + s];
        __syncthreads();
    }
    if (t < H) sS[t] = red[t];
    __syncthreads();

    // ---- pass C: acc = sum_e exp(logit-m) * h[src]  (divide at end) ------
    float acc = 0.f;
    for (int e0 = 0; e0 < deg; e0 += 64) {
        int ce = min(64, deg - e0);
        if (t < ce) ssrc[t] = csr_src[base + e0 + t];
        __syncthreads();
        for (int idx = t; idx < ce * H; idx += 128) {
            int e = idx / H, h = idx % H;
            float lg = a_s[(size_t)ssrc[e] * H + h] + adn[h];
            lg = lg >= 0.f ? lg : NEG_SLOPE * lg;
            ev[idx] = expf(lg - mS[h]);
        }
        __syncthreads();
        for (int e = 0; e < ce; ++e) {
            acc += ev[e * H + hh] * hbuf[(size_t)ssrc[e] * 128 + t];
        }
        __syncthreads();
    }
    acc *= 1.0f / (sS[hh] + 1e-16f);

    // bias + ELU + residual
    acc += bias[t];
    acc = acc > 0.f ? acc : (expf(acc) - 1.0f);
    if (RES) acc += xprev[(size_t)n * 128 + t];

    // LayerNorm over 128 channels
    red[t] = acc;
    __syncthreads();
    for (int s = 64; s > 0; s >>= 1) {
        if (t < s) red[t] += red[t + s];
        __syncthreads();
    }
    float mu = red[0] * (1.0f / 128.0f);
    __syncthreads();
    float dv = acc - mu;
    red[t] = dv * dv;
    __syncthreads();
    for (int s = 64; s > 0; s >>= 1) {
        if (t < s) red[t] += red[t + s];
        __syncthreads();
    }
    float var = red[0] * (1.0f / 128.0f);
    float y = dv * rsqrtf(var + 1e-5f) * ln_g[t] + ln_b[t];
    xout[(size_t)n * 128 + t] = y;
}

// ---------------------------------------------------------------------------
// fused prediction MLP: 16 rows per 128-thread block
// ---------------------------------------------------------------------------
__global__ __launch_bounds__(128) void mlp_kernel(const float* __restrict__ x,
                                                  const int* __restrict__ uidx,
                                                  const int* __restrict__ vidx, int num_users,
                                                  const float* __restrict__ mw1,
                                                  const float* __restrict__ mb1,
                                                  const float* __restrict__ mw2,
                                                  const float* __restrict__ mb2,
                                                  const float* __restrict__ mw3,
                                                  const float* __restrict__ mb3,
                                                  float* __restrict__ out, int B) {
    const int R = 16;
    __shared__ float comb[R][256];
    __shared__ float h1s[R][128];
    __shared__ float h2s[R][64];
    int t = threadIdx.x;
    int b0 = blockIdx.x * R;

    for (int r = 0; r < R; ++r) {
        int b = b0 + r;
        if (b < B) {
            int u = uidx[b];
            int v = vidx[b] + num_users;
            comb[r][t] = x[(size_t)u * 128 + t];
            comb[r][128 + t] = x[(size_t)v * 128 + t];
        } else {
            comb[r][t] = 0.f;
            comb[r][128 + t] = 0.f;
        }
    }
    __syncthreads();

    // h1 = relu(comb @ mw1 + mb1)  (col t)
    {
        float acc[R];
#pragma unroll
        for (int r = 0; r < R; ++r) acc[r] = mb1[t];
        for (int k = 0; k < 256; ++k) {
            float w = mw1[k * 128 + t];
#pragma unroll
            for (int r = 0; r < R; ++r) acc[r] += comb[r][k] * w;
        }
#pragma unroll
        for (int r = 0; r < R; ++r) h1s[r][t] = fmaxf(acc[r], 0.f);
    }
    __syncthreads();

    // h2 = relu(h1 @ mw2 + mb2)  (cols 0..63)
    if (t < 64) {
        float acc[R];
#pragma unroll
        for (int r = 0; r < R; ++r) acc[r] = mb2[t];
        for (int k = 0; k < 128; ++k) {
            float w = mw2[k * 64 + t];
#pragma unroll
            for (int r = 0; r < R; ++r) acc[r] += h1s[r][k] * w;
        }
#pragma unroll
        for (int r = 0; r < R; ++r) h2s[r][t] = fmaxf(acc[r], 0.f);
    }
    __syncthreads();

    // logits + sigmoid  (one row per thread)
    if (t < R) {
        int b = b0 + t;
        if (b < B) {
            float s = mb3[0];
#pragma unroll
            for (int k = 0; k < 64; ++k) s += h2s[t][k] * mw3[k];
            out[b] = 1.0f / (1.0f + expf(-s));
        }
    }
}

// ---------------------------------------------------------------------------
// launcher
// ---------------------------------------------------------------------------
extern "C" void kernel_launch(void* const* d_in, const int* in_sizes, int n_in,
                              void* d_out, int out_size, void* d_ws, size_t ws_size,
                              hipStream_t stream) {
    const int* uidx = (const int*)d_in[0];
    const int* vidx = (const int*)d_in[1];
    const int* eidx = (const int*)d_in[2];
    const float* utab = (const float*)d_in[3];
    const float* itab = (const float*)d_in[4];
    const float* W0 = (const float*)d_in[5];
    const float* as0 = (const float*)d_in[6];
    const float* ad0 = (const float*)d_in[7];
    const float* bb0 = (const float*)d_in[8];
    const float* W1 = (const float*)d_in[9];
    const float* as1 = (const float*)d_in[10];
    const float* ad1 = (const float*)d_in[11];
    const float* bb1 = (const float*)d_in[12];
    const float* W2 = (const float*)d_in[13];
    const float* as2 = (const float*)d_in[14];
    const float* ad2 = (const float*)d_in[15];
    const float* bb2 = (const float*)d_in[16];
    const float* ln_g = (const float*)d_in[17];
    const float* ln_b = (const float*)d_in[18];
    const float* mw1 = (const float*)d_in[19];
    const float* mb1 = (const float*)d_in[20];
    const float* mw2 = (const float*)d_in[21];
    const float* mb2 = (const float*)d_in[22];
    const float* mw3 = (const float*)d_in[23];
    const float* mb3 = (const float*)d_in[24];

    const int B = in_sizes[0];
    const int E = in_sizes[2] / 2;
    const int num_users = in_sizes[3] / D128;
    const int num_items = in_sizes[4] / D128;
    const int N = num_users + num_items;
    const int* esrc = eidx;
    const int* edst = eidx + E;

    // workspace carve-up
    size_t wsoff = 0;
    auto alloc = [&](size_t bytes) {
        void* p = (char*)d_ws + wsoff;
        wsoff += (bytes + 255) & ~(size_t)255;
        return p;
    };
    float* bufA = (float*)alloc((size_t)N * 128 * 4);
    float* bufB = (float*)alloc((size_t)N * 128 * 4);
    float* bufH = (float*)alloc((size_t)N * 128 * 4);
    float* aS = (float*)alloc((size_t)N * 4 * 4);
    float* aD = (float*)alloc((size_t)N * 4 * 4);
    int* cnt = (int*)alloc((size_t)(N + 1) * 4);
    int* off = (int*)alloc((size_t)(N + 1) * 4);
    int* cur = (int*)alloc((size_t)(N + 1) * 4);
    int* csr_src = (int*)alloc((size_t)E * 4);
    (void)ws_size;

    // x0 = concat(user_table, item_table)
    hipMemcpyAsync(bufA, utab, (size_t)num_users * 128 * 4, hipMemcpyDeviceToDevice, stream);
    hipMemcpyAsync(bufA + (size_t)num_users * 128, itab, (size_t)num_items * 128 * 4,
                   hipMemcpyDeviceToDevice, stream);

    // CSR by dst
    zero_int_kernel<<<(N + 255) / 256, 256, 0, stream>>>(cnt, N);
    count_kernel<<<(E + 255) / 256, 256, 0, stream>>>(edst, E, cnt);
    scan_kernel<<<1, 1024, 0, stream>>>(cnt, off, cur, N);
    fill_kernel<<<(E + 255) / 256, 256, 0, stream>>>(esrc, edst, E, cur, csr_src);

    const int gemm_grid = (N + 63) / 64;

    // ---- layer 0 (H=4, C=32, no residual) ----
    gemm128_kernel<<<gemm_grid, 256, 0, stream>>>(bufA, W0, bufH, N);
    att_kernel<4, 32><<<N, 128, 0, stream>>>(bufH, as0, ad0, aS, aD, N);
    agg_kernel<4, 32, false><<<N, 128, 0, stream>>>(bufH, aS, aD, off, csr_src, bufA, bb0,
                                                    ln_g, ln_b, bufB);
    // ---- layer 1 (H=4, C=32, residual) ----
    gemm128_kernel<<<gemm_grid, 256, 0, stream>>>(bufB, W1, bufH, N);
    att_kernel<4, 32><<<N, 128, 0, stream>>>(bufH, as1, ad1, aS, aD, N);
    agg_kernel<4, 32, true><<<N, 128, 0, stream>>>(bufH, aS, aD, off, csr_src, bufB, bb1,
                                                   ln_g, ln_b, bufA);
    // ---- layer 2 (H=1, C=128, residual) ----
    gemm128_kernel<<<gemm_grid, 256, 0, stream>>>(bufA, W2, bufH, N);
    att_kernel<1, 128><<<N, 128, 0, stream>>>(bufH, as2, ad2, aS, aD, N);
    agg_kernel<1, 128, true><<<N, 128, 0, stream>>>(bufH, aS, aD, off, csr_src, bufA, bb2,
                                                    ln_g, ln_b, bufB);

    // ---- prediction MLP ----
    mlp_kernel<<<(B + 15) / 16, 128, 0, stream>>>(bufB, uidx, vidx, num_users, mw1, mb1, mw2,
                                                  mb2, mw3, mb3, (float*)d_out, B);
}

// Round 2
// 602.844 us; speedup vs baseline: 1.2939x; 1.2939x over previous
//
#include <hip/hip_runtime.h>
#include <hip/hip_bf16.h>

#define D128 128
#define NEG_SLOPE 0.2f

// ---------------------------------------------------------------------------
// CSR build
// ---------------------------------------------------------------------------
__global__ void zero_int_kernel(int* __restrict__ p, int n) {
    int i = blockIdx.x * blockDim.x + threadIdx.x;
    if (i < n) p[i] = 0;
}

__global__ void count_kernel(const int* __restrict__ dst, int E, int* __restrict__ cnt) {
    int e = blockIdx.x * blockDim.x + threadIdx.x;
    if (e < E) atomicAdd(&cnt[dst[e]], 1);
}

// ---- hierarchical scan: local (2048/block) -> partials -> add ----
#define SB 256
#define SCAN_CHUNK 2048  // SB * 8

__global__ __launch_bounds__(SB) void scan_local_kernel(const int* __restrict__ cnt,
                                                        int* __restrict__ off,
                                                        int* __restrict__ partials, int N) {
    __shared__ int lds[SB];
    const int b = blockIdx.x;
    const int t = threadIdx.x;
    const int base = b * SCAN_CHUNK + t * 8;
    int v[8];
    int s = 0;
#pragma unroll
    for (int j = 0; j < 8; ++j) {
        int i = base + j;
        v[j] = (i < N) ? cnt[i] : 0;
        s += v[j];
    }
    lds[t] = s;
    __syncthreads();
    for (int d = 1; d < SB; d <<= 1) {
        int y = (t >= d) ? lds[t - d] : 0;
        __syncthreads();
        lds[t] += y;
        __syncthreads();
    }
    int pref = lds[t] - s;  // exclusive prefix of this thread's chunk within block
#pragma unroll
    for (int j = 0; j < 8; ++j) {
        int i = base + j;
        if (i < N) off[i] = pref;
        pref += v[j];
    }
    if (t == SB - 1) partials[b] = lds[t];
}

// single block, <=64 partials (N=70000 -> 35 blocks)
__global__ __launch_bounds__(64) void scan_partials_kernel(int* __restrict__ partials,
                                                           int* __restrict__ pp, int NB,
                                                           int* __restrict__ off, int N) {
    __shared__ int lds[64];
    int t = threadIdx.x;
    int v = (t < NB) ? partials[t] : 0;
    lds[t] = v;
    __syncthreads();
    for (int d = 1; d < 64; d <<= 1) {
        int y = (t >= d) ? lds[t - d] : 0;
        __syncthreads();
        lds[t] += y;
        __syncthreads();
    }
    pp[t] = lds[t] - v;  // exclusive
    if (t == 63) off[N] = lds[63];
}

__global__ void scan_add_kernel(int* __restrict__ off, int* __restrict__ cur,
                                const int* __restrict__ pp, int N) {
    int i = blockIdx.x * blockDim.x + threadIdx.x;
    if (i < N) {
        int o = off[i] + pp[i / SCAN_CHUNK];
        off[i] = o;
        cur[i] = o;
    }
}

__global__ void fill_kernel(const int* __restrict__ src, const int* __restrict__ dst, int E,
                            int* __restrict__ cur, int* __restrict__ csr_src) {
    int e = blockIdx.x * blockDim.x + threadIdx.x;
    if (e < E) {
        int p = atomicAdd(&cur[dst[e]], 1);
        csr_src[p] = src[e];
    }
}

// ---------------------------------------------------------------------------
// fp32 GEMM fused with attention scalars.
// Y[N,128] = X[N,128] @ W[128,128]; a_s[n,h]=sum_c Y[n,h*C+c]*att_s[h*C+c].
// 64 rows x 128 cols per block, 256 threads, 8 rows x 4 cols each.
// ---------------------------------------------------------------------------
template <int H, int C>
__global__ __launch_bounds__(256) void gemm_att_kernel(const float* __restrict__ X,
                                                       const float* __restrict__ W,
                                                       const float* __restrict__ att_s,
                                                       const float* __restrict__ att_d,
                                                       float* __restrict__ Y,
                                                       float* __restrict__ a_s,
                                                       float* __restrict__ a_d, int N) {
    __shared__ float xs[64][128];
    const int t = threadIdx.x;
    const int row0 = blockIdx.x * 64;

    // stage X tile (float4, coalesced)
    for (int i = t; i < 64 * 128 / 4; i += 256) {
        int elem = i * 4;
        int r = elem / 128, c = elem % 128;
        int gr = row0 + r;
        float4 v = make_float4(0.f, 0.f, 0.f, 0.f);
        if (gr < N) v = *(const float4*)&X[(size_t)gr * 128 + c];
        *(float4*)&xs[r][c] = v;
    }
    __syncthreads();

    const int c0 = (t & 31) * 4;
    const int r0 = (t >> 5) * 8;
    float acc[8][4];
#pragma unroll
    for (int r = 0; r < 8; ++r)
#pragma unroll
        for (int j = 0; j < 4; ++j) acc[r][j] = 0.f;

    for (int k = 0; k < 128; ++k) {
        float4 w = *(const float4*)&W[k * 128 + c0];
#pragma unroll
        for (int r = 0; r < 8; ++r) {
            float xv = xs[r0 + r][k];
            acc[r][0] += xv * w.x;
            acc[r][1] += xv * w.y;
            acc[r][2] += xv * w.z;
            acc[r][3] += xv * w.w;
        }
    }

    const float4 asv = *(const float4*)&att_s[c0];
    const float4 adv = *(const float4*)&att_d[c0];
#pragma unroll
    for (int r = 0; r < 8; ++r) {
        int gr = row0 + r0 + r;
        if (gr < N)
            *(float4*)&Y[(size_t)gr * 128 + c0] =
                make_float4(acc[r][0], acc[r][1], acc[r][2], acc[r][3]);
        // per-head attention dot products via cross-lane reduce
        float ps = acc[r][0] * asv.x + acc[r][1] * asv.y + acc[r][2] * asv.z + acc[r][3] * asv.w;
        float pd = acc[r][0] * adv.x + acc[r][1] * adv.y + acc[r][2] * adv.z + acc[r][3] * adv.w;
#pragma unroll
        for (int m = 1; m < C / 4; m <<= 1) {
            ps += __shfl_xor(ps, m);
            pd += __shfl_xor(pd, m);
        }
        if ((t & (C / 4 - 1)) == 0 && gr < N) {
            int head = c0 / C;
            a_s[(size_t)gr * H + head] = ps;
            a_d[(size_t)gr * H + head] = pd;
        }
    }
}

// ---------------------------------------------------------------------------
// aggregation + bias + ELU + residual + LayerNorm.  One node per 128-thr block.
// ---------------------------------------------------------------------------
template <int H, int C, bool RES>
__global__ __launch_bounds__(128) void agg_kernel(const float* __restrict__ hbuf,
                                                  const float* __restrict__ a_s,
                                                  const float* __restrict__ a_d,
                                                  const int* __restrict__ off,
                                                  const int* __restrict__ csr_src,
                                                  const float* __restrict__ xprev,
                                                  const float* __restrict__ bias,
                                                  const float* __restrict__ ln_g,
                                                  const float* __restrict__ ln_b,
                                                  float* __restrict__ xout) {
    const int n = blockIdx.x;
    const int t = threadIdx.x;          // 0..127
    const int hh = t / C;               // head of this channel
    const int base = off[n];
    const int deg = off[n + 1] - base;

    __shared__ float adn[H];
    __shared__ float mS[H], sS[H];
    __shared__ float red[128];
    __shared__ int ssrc[64];
    __shared__ float ev[64 * H];

    if (t < H) adn[t] = a_d[(size_t)n * H + t];
    __syncthreads();

    // ---- pass A: per-head max of leaky_relu(a_s[src]+a_d[n]) -------------
    float pm = -1e30f;
    for (int idx = t; idx < deg * H; idx += 128) {
        int e = idx / H, h = idx % H;
        int s = csr_src[base + e];
        float lg = a_s[(size_t)s * H + h] + adn[h];
        lg = lg >= 0.f ? lg : NEG_SLOPE * lg;
        pm = fmaxf(pm, lg);
    }
    red[t] = pm;
    __syncthreads();
    for (int s = 64; s >= H; s >>= 1) {
        if (t < s) red[t] = fmaxf(red[t], red[t + s]);
        __syncthreads();
    }
    if (t < H) mS[t] = red[t];
    __syncthreads();

    // ---- pass B: per-head sum of exp(logit - m) --------------------------
    float ps = 0.f;
    for (int idx = t; idx < deg * H; idx += 128) {
        int e = idx / H, h = idx % H;
        int s = csr_src[base + e];
        float lg = a_s[(size_t)s * H + h] + adn[h];
        lg = lg >= 0.f ? lg : NEG_SLOPE * lg;
        ps += expf(lg - mS[h]);
    }
    red[t] = ps;
    __syncthreads();
    for (int s = 64; s >= H; s >>= 1) {
        if (t < s) red[t] += red[t + s];
        __syncthreads();
    }
    if (t < H) sS[t] = red[t];
    __syncthreads();

    // ---- pass C: acc = sum_e exp(logit-m) * h[src]  (divide at end) ------
    float acc = 0.f;
    for (int e0 = 0; e0 < deg; e0 += 64) {
        int ce = min(64, deg - e0);
        if (t < ce) ssrc[t] = csr_src[base + e0 + t];
        __syncthreads();
        for (int idx = t; idx < ce * H; idx += 128) {
            int e = idx / H, h = idx % H;
            float lg = a_s[(size_t)ssrc[e] * H + h] + adn[h];
            lg = lg >= 0.f ? lg : NEG_SLOPE * lg;
            ev[idx] = expf(lg - mS[h]);
        }
        __syncthreads();
        for (int e = 0; e < ce; ++e) {
            acc += ev[e * H + hh] * hbuf[(size_t)ssrc[e] * 128 + t];
        }
        __syncthreads();
    }
    acc *= 1.0f / (sS[hh] + 1e-16f);

    // bias + ELU + residual
    acc += bias[t];
    acc = acc > 0.f ? acc : (expf(acc) - 1.0f);
    if (RES) acc += xprev[(size_t)n * 128 + t];

    // LayerNorm over 128 channels
    red[t] = acc;
    __syncthreads();
    for (int s = 64; s > 0; s >>= 1) {
        if (t < s) red[t] += red[t + s];
        __syncthreads();
    }
    float mu = red[0] * (1.0f / 128.0f);
    __syncthreads();
    float dv = acc - mu;
    red[t] = dv * dv;
    __syncthreads();
    for (int s = 64; s > 0; s >>= 1) {
        if (t < s) red[t] += red[t + s];
        __syncthreads();
    }
    float var = red[0] * (1.0f / 128.0f);
    float y = dv * rsqrtf(var + 1e-5f) * ln_g[t] + ln_b[t];
    xout[(size_t)n * 128 + t] = y;
}

// ---------------------------------------------------------------------------
// fused prediction MLP: 16 rows per 128-thread block
// ---------------------------------------------------------------------------
__global__ __launch_bounds__(128) void mlp_kernel(const float* __restrict__ x,
                                                  const int* __restrict__ uidx,
                                                  const int* __restrict__ vidx, int num_users,
                                                  const float* __restrict__ mw1,
                                                  const float* __restrict__ mb1,
                                                  const float* __restrict__ mw2,
                                                  const float* __restrict__ mb2,
                                                  const float* __restrict__ mw3,
                                                  const float* __restrict__ mb3,
                                                  float* __restrict__ out, int B) {
    const int R = 16;
    __shared__ float comb[R][256];
    __shared__ float h1s[R][128];
    __shared__ float h2s[R][64];
    int t = threadIdx.x;
    int b0 = blockIdx.x * R;

    for (int r = 0; r < R; ++r) {
        int b = b0 + r;
        if (b < B) {
            int u = uidx[b];
            int v = vidx[b] + num_users;
            comb[r][t] = x[(size_t)u * 128 + t];
            comb[r][128 + t] = x[(size_t)v * 128 + t];
        } else {
            comb[r][t] = 0.f;
            comb[r][128 + t] = 0.f;
        }
    }
    __syncthreads();

    // h1 = relu(comb @ mw1 + mb1)  (col t)
    {
        float acc[R];
#pragma unroll
        for (int r = 0; r < R; ++r) acc[r] = mb1[t];
        for (int k = 0; k < 256; ++k) {
            float w = mw1[k * 128 + t];
#pragma unroll
            for (int r = 0; r < R; ++r) acc[r] += comb[r][k] * w;
        }
#pragma unroll
        for (int r = 0; r < R; ++r) h1s[r][t] = fmaxf(acc[r], 0.f);
    }
    __syncthreads();

    // h2 = relu(h1 @ mw2 + mb2)  (cols 0..63)
    if (t < 64) {
        float acc[R];
#pragma unroll
        for (int r = 0; r < R; ++r) acc[r] = mb2[t];
        for (int k = 0; k < 128; ++k) {
            float w = mw2[k * 64 + t];
#pragma unroll
            for (int r = 0; r < R; ++r) acc[r] += h1s[r][k] * w;
        }
#pragma unroll
        for (int r = 0; r < R; ++r) h2s[r][t] = fmaxf(acc[r], 0.f);
    }
    __syncthreads();

    // logits + sigmoid  (one row per thread)
    if (t < R) {
        int b = b0 + t;
        if (b < B) {
            float s = mb3[0];
#pragma unroll
            for (int k = 0; k < 64; ++k) s += h2s[t][k] * mw3[k];
            out[b] = 1.0f / (1.0f + expf(-s));
        }
    }
}

// ---------------------------------------------------------------------------
// launcher
// ---------------------------------------------------------------------------
extern "C" void kernel_launch(void* const* d_in, const int* in_sizes, int n_in,
                              void* d_out, int out_size, void* d_ws, size_t ws_size,
                              hipStream_t stream) {
    const int* uidx = (const int*)d_in[0];
    const int* vidx = (const int*)d_in[1];
    const int* eidx = (const int*)d_in[2];
    const float* utab = (const float*)d_in[3];
    const float* itab = (const float*)d_in[4];
    const float* W0 = (const float*)d_in[5];
    const float* as0 = (const float*)d_in[6];
    const float* ad0 = (const float*)d_in[7];
    const float* bb0 = (const float*)d_in[8];
    const float* W1 = (const float*)d_in[9];
    const float* as1 = (const float*)d_in[10];
    const float* ad1 = (const float*)d_in[11];
    const float* bb1 = (const float*)d_in[12];
    const float* W2 = (const float*)d_in[13];
    const float* as2 = (const float*)d_in[14];
    const float* ad2 = (const float*)d_in[15];
    const float* bb2 = (const float*)d_in[16];
    const float* ln_g = (const float*)d_in[17];
    const float* ln_b = (const float*)d_in[18];
    const float* mw1 = (const float*)d_in[19];
    const float* mb1 = (const float*)d_in[20];
    const float* mw2 = (const float*)d_in[21];
    const float* mb2 = (const float*)d_in[22];
    const float* mw3 = (const float*)d_in[23];
    const float* mb3 = (const float*)d_in[24];

    const int B = in_sizes[0];
    const int E = in_sizes[2] / 2;
    const int num_users = in_sizes[3] / D128;
    const int num_items = in_sizes[4] / D128;
    const int N = num_users + num_items;
    const int* esrc = eidx;
    const int* edst = eidx + E;

    // workspace carve-up
    size_t wsoff = 0;
    auto alloc = [&](size_t bytes) {
        void* p = (char*)d_ws + wsoff;
        wsoff += (bytes + 255) & ~(size_t)255;
        return p;
    };
    float* bufA = (float*)alloc((size_t)N * 128 * 4);
    float* bufB = (float*)alloc((size_t)N * 128 * 4);
    float* bufH = (float*)alloc((size_t)N * 128 * 4);
    float* aS = (float*)alloc((size_t)N * 4 * 4);
    float* aD = (float*)alloc((size_t)N * 4 * 4);
    int* cnt = (int*)alloc((size_t)(N + 1) * 4);
    int* off = (int*)alloc((size_t)(N + 1) * 4);
    int* cur = (int*)alloc((size_t)(N + 1) * 4);
    int* csr_src = (int*)alloc((size_t)E * 4);
    int* partials = (int*)alloc(64 * 4);
    int* pp = (int*)alloc(64 * 4);
    (void)ws_size;

    // x0 = concat(user_table, item_table)
    hipMemcpyAsync(bufA, utab, (size_t)num_users * 128 * 4, hipMemcpyDeviceToDevice, stream);
    hipMemcpyAsync(bufA + (size_t)num_users * 128, itab, (size_t)num_items * 128 * 4,
                   hipMemcpyDeviceToDevice, stream);

    // CSR by dst (hierarchical scan)
    const int NB = (N + SCAN_CHUNK - 1) / SCAN_CHUNK;  // 35 for N=70000 (<=64 required)
    zero_int_kernel<<<(N + 255) / 256, 256, 0, stream>>>(cnt, N);
    count_kernel<<<(E + 255) / 256, 256, 0, stream>>>(edst, E, cnt);
    scan_local_kernel<<<NB, SB, 0, stream>>>(cnt, off, partials, N);
    scan_partials_kernel<<<1, 64, 0, stream>>>(partials, pp, NB, off, N);
    scan_add_kernel<<<(N + 255) / 256, 256, 0, stream>>>(off, cur, pp, N);
    fill_kernel<<<(E + 255) / 256, 256, 0, stream>>>(esrc, edst, E, cur, csr_src);

    const int gemm_grid = (N + 63) / 64;

    // ---- layer 0 (H=4, C=32, no residual) ----
    gemm_att_kernel<4, 32><<<gemm_grid, 256, 0, stream>>>(bufA, W0, as0, ad0, bufH, aS, aD, N);
    agg_kernel<4, 32, false><<<N, 128, 0, stream>>>(bufH, aS, aD, off, csr_src, bufA, bb0,
                                                    ln_g, ln_b, bufB);
    // ---- layer 1 (H=4, C=32, residual) ----
    gemm_att_kernel<4, 32><<<gemm_grid, 256, 0, stream>>>(bufB, W1, as1, ad1, bufH, aS, aD, N);
    agg_kernel<4, 32, true><<<N, 128, 0, stream>>>(bufH, aS, aD, off, csr_src, bufB, bb1,
                                                   ln_g, ln_b, bufA);
    // ---- layer 2 (H=1, C=128, residual) ----
    gemm_att_kernel<1, 128><<<gemm_grid, 256, 0, stream>>>(bufA, W2, as2, ad2, bufH, aS, aD, N);
    agg_kernel<1, 128, true><<<N, 128, 0, stream>>>(bufH, aS, aD, off, csr_src, bufA, bb2,
                                                    ln_g, ln_b, bufB);

    // ---- prediction MLP ----
    mlp_kernel<<<(B + 15) / 16, 128, 0, stream>>>(bufB, uidx, vidx, num_users, mw1, mb1, mw2,
                                                  mb2, mw3, mb3, (float*)d_out, B);
}

// Round 3
// 442.544 us; speedup vs baseline: 1.7626x; 1.3622x over previous
//
#include <hip/hip_runtime.h>
#include <hip/hip_bf16.h>

#define D128 128
#define NEG_SLOPE 0.2f

// ---------------------------------------------------------------------------
// CSR build
// ---------------------------------------------------------------------------
__global__ void zero_int_kernel(int* __restrict__ p, int n) {
    int i = blockIdx.x * blockDim.x + threadIdx.x;
    if (i < n) p[i] = 0;
}

__global__ void count_kernel(const int* __restrict__ dst, int E, int* __restrict__ cnt) {
    int e = blockIdx.x * blockDim.x + threadIdx.x;
    if (e < E) atomicAdd(&cnt[dst[e]], 1);
}

// ---- hierarchical scan: local (2048/block) -> partials -> add ----
#define SB 256
#define SCAN_CHUNK 2048  // SB * 8

__global__ __launch_bounds__(SB) void scan_local_kernel(const int* __restrict__ cnt,
                                                        int* __restrict__ off,
                                                        int* __restrict__ partials, int N) {
    __shared__ int lds[SB];
    const int b = blockIdx.x;
    const int t = threadIdx.x;
    const int base = b * SCAN_CHUNK + t * 8;
    int v[8];
    int s = 0;
#pragma unroll
    for (int j = 0; j < 8; ++j) {
        int i = base + j;
        v[j] = (i < N) ? cnt[i] : 0;
        s += v[j];
    }
    lds[t] = s;
    __syncthreads();
    for (int d = 1; d < SB; d <<= 1) {
        int y = (t >= d) ? lds[t - d] : 0;
        __syncthreads();
        lds[t] += y;
        __syncthreads();
    }
    int pref = lds[t] - s;
#pragma unroll
    for (int j = 0; j < 8; ++j) {
        int i = base + j;
        if (i < N) off[i] = pref;
        pref += v[j];
    }
    if (t == SB - 1) partials[b] = lds[t];
}

__global__ __launch_bounds__(64) void scan_partials_kernel(int* __restrict__ partials,
                                                           int* __restrict__ pp, int NB,
                                                           int* __restrict__ off, int N) {
    __shared__ int lds[64];
    int t = threadIdx.x;
    int v = (t < NB) ? partials[t] : 0;
    lds[t] = v;
    __syncthreads();
    for (int d = 1; d < 64; d <<= 1) {
        int y = (t >= d) ? lds[t - d] : 0;
        __syncthreads();
        lds[t] += y;
        __syncthreads();
    }
    pp[t] = lds[t] - v;
    if (t == 63) off[N] = lds[63];
}

__global__ void scan_add_kernel(int* __restrict__ off, int* __restrict__ cur,
                                const int* __restrict__ pp, int N) {
    int i = blockIdx.x * blockDim.x + threadIdx.x;
    if (i < N) {
        int o = off[i] + pp[i / SCAN_CHUNK];
        off[i] = o;
        cur[i] = o;
    }
}

__global__ void fill_kernel(const int* __restrict__ src, const int* __restrict__ dst, int E,
                            int* __restrict__ cur, int* __restrict__ csr_src) {
    int e = blockIdx.x * blockDim.x + threadIdx.x;
    if (e < E) {
        int p = atomicAdd(&cur[dst[e]], 1);
        csr_src[p] = src[e];
    }
}

// ---------------------------------------------------------------------------
// fp32 GEMM fused with attention scalars.
// ---------------------------------------------------------------------------
template <int H, int C>
__global__ __launch_bounds__(256) void gemm_att_kernel(const float* __restrict__ X,
                                                       const float* __restrict__ W,
                                                       const float* __restrict__ att_s,
                                                       const float* __restrict__ att_d,
                                                       float* __restrict__ Y,
                                                       float* __restrict__ a_s,
                                                       float* __restrict__ a_d, int N) {
    __shared__ float xs[64][128];
    const int t = threadIdx.x;
    const int row0 = blockIdx.x * 64;

    for (int i = t; i < 64 * 128 / 4; i += 256) {
        int elem = i * 4;
        int r = elem / 128, c = elem % 128;
        int gr = row0 + r;
        float4 v = make_float4(0.f, 0.f, 0.f, 0.f);
        if (gr < N) v = *(const float4*)&X[(size_t)gr * 128 + c];
        *(float4*)&xs[r][c] = v;
    }
    __syncthreads();

    const int c0 = (t & 31) * 4;
    const int r0 = (t >> 5) * 8;
    float acc[8][4];
#pragma unroll
    for (int r = 0; r < 8; ++r)
#pragma unroll
        for (int j = 0; j < 4; ++j) acc[r][j] = 0.f;

    for (int k = 0; k < 128; ++k) {
        float4 w = *(const float4*)&W[k * 128 + c0];
#pragma unroll
        for (int r = 0; r < 8; ++r) {
            float xv = xs[r0 + r][k];
            acc[r][0] += xv * w.x;
            acc[r][1] += xv * w.y;
            acc[r][2] += xv * w.z;
            acc[r][3] += xv * w.w;
        }
    }

    const float4 asv = *(const float4*)&att_s[c0];
    const float4 adv = *(const float4*)&att_d[c0];
#pragma unroll
    for (int r = 0; r < 8; ++r) {
        int gr = row0 + r0 + r;
        if (gr < N)
            *(float4*)&Y[(size_t)gr * 128 + c0] =
                make_float4(acc[r][0], acc[r][1], acc[r][2], acc[r][3]);
        float ps = acc[r][0] * asv.x + acc[r][1] * asv.y + acc[r][2] * asv.z + acc[r][3] * asv.w;
        float pd = acc[r][0] * adv.x + acc[r][1] * adv.y + acc[r][2] * adv.z + acc[r][3] * adv.w;
#pragma unroll
        for (int m = 1; m < C / 4; m <<= 1) {
            ps += __shfl_xor(ps, m);
            pd += __shfl_xor(pd, m);
        }
        if ((t & (C / 4 - 1)) == 0 && gr < N) {
            int head = c0 / C;
            a_s[(size_t)gr * H + head] = ps;
            a_d[(size_t)gr * H + head] = pd;
        }
    }
}

// ---------------------------------------------------------------------------
// aggregation + bias + ELU + residual + LayerNorm.  One node per 128-thr block.
// Single pass over edges: softmax without max-subtraction (shift-invariant,
// logits bounded small), sum and weighted accumulate fused.
// Thread layout: g = t>>5 (edge group, stride 4), lane = t&31 (channel quad).
// ---------------------------------------------------------------------------
template <int H, int C, bool RES>
__global__ __launch_bounds__(128) void agg_kernel(const float* __restrict__ hbuf,
                                                  const float* __restrict__ a_s,
                                                  const float* __restrict__ a_d,
                                                  const int* __restrict__ off,
                                                  const int* __restrict__ csr_src,
                                                  const float* __restrict__ xprev,
                                                  const float* __restrict__ bias,
                                                  const float* __restrict__ ln_g,
                                                  const float* __restrict__ ln_b,
                                                  float* __restrict__ xout) {
    const int n = blockIdx.x;
    const int t = threadIdx.x;   // 0..127
    const int lane = t & 31;
    const int g = t >> 5;        // 0..3
    const int c4 = lane * 4;
    const int head = c4 / C;
    const int base = off[n];
    const int deg = off[n + 1] - base;

    __shared__ float4 red4[4][32];
    __shared__ float redp[4][32];
    __shared__ float chan[128];
    __shared__ float red[128];

    const float adn = a_d[(size_t)n * H + head];
    float ax = 0.f, ay = 0.f, az = 0.f, aw = 0.f;
    float psum = 0.f;

#define AGG_BODY(EE)                                                        \
    {                                                                       \
        int s_ = csr_src[base + (EE)];                                      \
        float lg_ = a_s[(size_t)s_ * H + head] + adn;                       \
        lg_ = lg_ >= 0.f ? lg_ : NEG_SLOPE * lg_;                           \
        float p_ = expf(lg_);                                               \
        const float4 hv_ = *(const float4*)&hbuf[(size_t)s_ * 128 + c4];    \
        psum += p_;                                                         \
        ax += p_ * hv_.x; ay += p_ * hv_.y;                                 \
        az += p_ * hv_.z; aw += p_ * hv_.w;                                 \
    }

    int e = g;
    for (; e + 4 < deg; e += 8) {
        AGG_BODY(e);
        AGG_BODY(e + 4);
    }
    if (e < deg) AGG_BODY(e);
#undef AGG_BODY

    red4[g][lane] = make_float4(ax, ay, az, aw);
    redp[g][lane] = psum;
    __syncthreads();

    if (g == 0) {
        float4 a0 = red4[0][lane], a1 = red4[1][lane], a2 = red4[2][lane], a3 = red4[3][lane];
        float ps = redp[0][lane] + redp[1][lane] + redp[2][lane] + redp[3][lane];
        float inv = 1.0f / (ps + 1e-16f);
        chan[c4 + 0] = (a0.x + a1.x + a2.x + a3.x) * inv;
        chan[c4 + 1] = (a0.y + a1.y + a2.y + a3.y) * inv;
        chan[c4 + 2] = (a0.z + a1.z + a2.z + a3.z) * inv;
        chan[c4 + 3] = (a0.w + a1.w + a2.w + a3.w) * inv;
    }
    __syncthreads();

    // bias + ELU + residual
    float acc = chan[t] + bias[t];
    acc = acc > 0.f ? acc : (expf(acc) - 1.0f);
    if (RES) acc += xprev[(size_t)n * 128 + t];

    // LayerNorm over 128 channels
    red[t] = acc;
    __syncthreads();
    for (int s = 64; s > 0; s >>= 1) {
        if (t < s) red[t] += red[t + s];
        __syncthreads();
    }
    float mu = red[0] * (1.0f / 128.0f);
    __syncthreads();
    float dv = acc - mu;
    red[t] = dv * dv;
    __syncthreads();
    for (int s = 64; s > 0; s >>= 1) {
        if (t < s) red[t] += red[t + s];
        __syncthreads();
    }
    float var = red[0] * (1.0f / 128.0f);
    float y = dv * rsqrtf(var + 1e-5f) * ln_g[t] + ln_b[t];
    xout[(size_t)n * 128 + t] = y;
}

// ---------------------------------------------------------------------------
// fused prediction MLP: 16 rows per 128-thread block
// ---------------------------------------------------------------------------
__global__ __launch_bounds__(128) void mlp_kernel(const float* __restrict__ x,
                                                  const int* __restrict__ uidx,
                                                  const int* __restrict__ vidx, int num_users,
                                                  const float* __restrict__ mw1,
                                                  const float* __restrict__ mb1,
                                                  const float* __restrict__ mw2,
                                                  const float* __restrict__ mb2,
                                                  const float* __restrict__ mw3,
                                                  const float* __restrict__ mb3,
                                                  float* __restrict__ out, int B) {
    const int R = 16;
    __shared__ float comb[R][256];
    __shared__ float h1s[R][128];
    __shared__ float h2s[R][64];
    int t = threadIdx.x;
    int b0 = blockIdx.x * R;

    for (int r = 0; r < R; ++r) {
        int b = b0 + r;
        if (b < B) {
            int u = uidx[b];
            int v = vidx[b] + num_users;
            comb[r][t] = x[(size_t)u * 128 + t];
            comb[r][128 + t] = x[(size_t)v * 128 + t];
        } else {
            comb[r][t] = 0.f;
            comb[r][128 + t] = 0.f;
        }
    }
    __syncthreads();

    {
        float acc[R];
#pragma unroll
        for (int r = 0; r < R; ++r) acc[r] = mb1[t];
        for (int k = 0; k < 256; ++k) {
            float w = mw1[k * 128 + t];
#pragma unroll
            for (int r = 0; r < R; ++r) acc[r] += comb[r][k] * w;
        }
#pragma unroll
        for (int r = 0; r < R; ++r) h1s[r][t] = fmaxf(acc[r], 0.f);
    }
    __syncthreads();

    if (t < 64) {
        float acc[R];
#pragma unroll
        for (int r = 0; r < R; ++r) acc[r] = mb2[t];
        for (int k = 0; k < 128; ++k) {
            float w = mw2[k * 64 + t];
#pragma unroll
            for (int r = 0; r < R; ++r) acc[r] += h1s[r][k] * w;
        }
#pragma unroll
        for (int r = 0; r < R; ++r) h2s[r][t] = fmaxf(acc[r], 0.f);
    }
    __syncthreads();

    if (t < R) {
        int b = b0 + t;
        if (b < B) {
            float s = mb3[0];
#pragma unroll
            for (int k = 0; k < 64; ++k) s += h2s[t][k] * mw3[k];
            out[b] = 1.0f / (1.0f + expf(-s));
        }
    }
}

// ---------------------------------------------------------------------------
// launcher
// ---------------------------------------------------------------------------
extern "C" void kernel_launch(void* const* d_in, const int* in_sizes, int n_in,
                              void* d_out, int out_size, void* d_ws, size_t ws_size,
                              hipStream_t stream) {
    const int* uidx = (const int*)d_in[0];
    const int* vidx = (const int*)d_in[1];
    const int* eidx = (const int*)d_in[2];
    const float* utab = (const float*)d_in[3];
    const float* itab = (const float*)d_in[4];
    const float* W0 = (const float*)d_in[5];
    const float* as0 = (const float*)d_in[6];
    const float* ad0 = (const float*)d_in[7];
    const float* bb0 = (const float*)d_in[8];
    const float* W1 = (const float*)d_in[9];
    const float* as1 = (const float*)d_in[10];
    const float* ad1 = (const float*)d_in[11];
    const float* bb1 = (const float*)d_in[12];
    const float* W2 = (const float*)d_in[13];
    const float* as2 = (const float*)d_in[14];
    const float* ad2 = (const float*)d_in[15];
    const float* bb2 = (const float*)d_in[16];
    const float* ln_g = (const float*)d_in[17];
    const float* ln_b = (const float*)d_in[18];
    const float* mw1 = (const float*)d_in[19];
    const float* mb1 = (const float*)d_in[20];
    const float* mw2 = (const float*)d_in[21];
    const float* mb2 = (const float*)d_in[22];
    const float* mw3 = (const float*)d_in[23];
    const float* mb3 = (const float*)d_in[24];

    const int B = in_sizes[0];
    const int E = in_sizes[2] / 2;
    const int num_users = in_sizes[3] / D128;
    const int num_items = in_sizes[4] / D128;
    const int N = num_users + num_items;
    const int* esrc = eidx;
    const int* edst = eidx + E;

    size_t wsoff = 0;
    auto alloc = [&](size_t bytes) {
        void* p = (char*)d_ws + wsoff;
        wsoff += (bytes + 255) & ~(size_t)255;
        return p;
    };
    float* bufA = (float*)alloc((size_t)N * 128 * 4);
    float* bufB = (float*)alloc((size_t)N * 128 * 4);
    float* bufH = (float*)alloc((size_t)N * 128 * 4);
    float* aS = (float*)alloc((size_t)N * 4 * 4);
    float* aD = (float*)alloc((size_t)N * 4 * 4);
    int* cnt = (int*)alloc((size_t)(N + 1) * 4);
    int* off = (int*)alloc((size_t)(N + 1) * 4);
    int* cur = (int*)alloc((size_t)(N + 1) * 4);
    int* csr_src = (int*)alloc((size_t)E * 4);
    int* partials = (int*)alloc(64 * 4);
    int* pp = (int*)alloc(64 * 4);
    (void)ws_size;

    hipMemcpyAsync(bufA, utab, (size_t)num_users * 128 * 4, hipMemcpyDeviceToDevice, stream);
    hipMemcpyAsync(bufA + (size_t)num_users * 128, itab, (size_t)num_items * 128 * 4,
                   hipMemcpyDeviceToDevice, stream);

    const int NB = (N + SCAN_CHUNK - 1) / SCAN_CHUNK;
    zero_int_kernel<<<(N + 255) / 256, 256, 0, stream>>>(cnt, N);
    count_kernel<<<(E + 255) / 256, 256, 0, stream>>>(edst, E, cnt);
    scan_local_kernel<<<NB, SB, 0, stream>>>(cnt, off, partials, N);
    scan_partials_kernel<<<1, 64, 0, stream>>>(partials, pp, NB, off, N);
    scan_add_kernel<<<(N + 255) / 256, 256, 0, stream>>>(off, cur, pp, N);
    fill_kernel<<<(E + 255) / 256, 256, 0, stream>>>(esrc, edst, E, cur, csr_src);

    const int gemm_grid = (N + 63) / 64;

    // ---- layer 0 (H=4, C=32, no residual) ----
    gemm_att_kernel<4, 32><<<gemm_grid, 256, 0, stream>>>(bufA, W0, as0, ad0, bufH, aS, aD, N);
    agg_kernel<4, 32, false><<<N, 128, 0, stream>>>(bufH, aS, aD, off, csr_src, bufA, bb0,
                                                    ln_g, ln_b, bufB);
    // ---- layer 1 (H=4, C=32, residual) ----
    gemm_att_kernel<4, 32><<<gemm_grid, 256, 0, stream>>>(bufB, W1, as1, ad1, bufH, aS, aD, N);
    agg_kernel<4, 32, true><<<N, 128, 0, stream>>>(bufH, aS, aD, off, csr_src, bufB, bb1,
                                                   ln_g, ln_b, bufA);
    // ---- layer 2 (H=1, C=128, residual) ----
    gemm_att_kernel<1, 128><<<gemm_grid, 256, 0, stream>>>(bufA, W2, as2, ad2, bufH, aS, aD, N);
    agg_kernel<1, 128, true><<<N, 128, 0, stream>>>(bufH, aS, aD, off, csr_src, bufA, bb2,
                                                    ln_g, ln_b, bufB);

    // ---- prediction MLP ----
    mlp_kernel<<<(B + 15) / 16, 128, 0, stream>>>(bufB, uidx, vidx, num_users, mw1, mb1, mw2,
                                                  mb2, mw3, mb3, (float*)d_out, B);
}

// Round 4
// 400.865 us; speedup vs baseline: 1.9459x; 1.1040x over previous
//
#include <hip/hip_runtime.h>
#include <hip/hip_bf16.h>

#define D128 128
#define NEG_SLOPE 0.2f

__device__ inline float bf2f(unsigned short u) {
    return __uint_as_float(((unsigned)u) << 16);
}
__device__ inline unsigned short f2bf(float f) {  // RTNE
    unsigned u = __float_as_uint(f);
    unsigned r = (u + 0x7fffu + ((u >> 16) & 1u)) >> 16;
    return (unsigned short)r;
}

// ---------------------------------------------------------------------------
// CSR build
// ---------------------------------------------------------------------------
__global__ void zero_int_kernel(int* __restrict__ p, int n) {
    int i = blockIdx.x * blockDim.x + threadIdx.x;
    if (i < n) p[i] = 0;
}

__global__ void count_kernel(const int* __restrict__ dst, int E, int* __restrict__ cnt) {
    int e = blockIdx.x * blockDim.x + threadIdx.x;
    if (e < E) atomicAdd(&cnt[dst[e]], 1);
}

#define SB 256
#define SCAN_CHUNK 2048  // SB * 8

__global__ __launch_bounds__(SB) void scan_local_kernel(const int* __restrict__ cnt,
                                                        int* __restrict__ off,
                                                        int* __restrict__ partials, int N) {
    __shared__ int lds[SB];
    const int b = blockIdx.x;
    const int t = threadIdx.x;
    const int base = b * SCAN_CHUNK + t * 8;
    int v[8];
    int s = 0;
#pragma unroll
    for (int j = 0; j < 8; ++j) {
        int i = base + j;
        v[j] = (i < N) ? cnt[i] : 0;
        s += v[j];
    }
    lds[t] = s;
    __syncthreads();
    for (int d = 1; d < SB; d <<= 1) {
        int y = (t >= d) ? lds[t - d] : 0;
        __syncthreads();
        lds[t] += y;
        __syncthreads();
    }
    int pref = lds[t] - s;
#pragma unroll
    for (int j = 0; j < 8; ++j) {
        int i = base + j;
        if (i < N) off[i] = pref;
        pref += v[j];
    }
    if (t == SB - 1) partials[b] = lds[t];
}

__global__ __launch_bounds__(64) void scan_partials_kernel(int* __restrict__ partials,
                                                           int* __restrict__ pp, int NB,
                                                           int* __restrict__ off, int N) {
    __shared__ int lds[64];
    int t = threadIdx.x;
    int v = (t < NB) ? partials[t] : 0;
    lds[t] = v;
    __syncthreads();
    for (int d = 1; d < 64; d <<= 1) {
        int y = (t >= d) ? lds[t - d] : 0;
        __syncthreads();
        lds[t] += y;
        __syncthreads();
    }
    pp[t] = lds[t] - v;
    if (t == 63) off[N] = lds[63];
}

__global__ void scan_add_kernel(int* __restrict__ off, int* __restrict__ cur,
                                const int* __restrict__ pp, int N) {
    int i = blockIdx.x * blockDim.x + threadIdx.x;
    if (i < N) {
        int o = off[i] + pp[i / SCAN_CHUNK];
        off[i] = o;
        cur[i] = o;
    }
}

__global__ void fill_kernel(const int* __restrict__ src, const int* __restrict__ dst, int E,
                            int* __restrict__ cur, int* __restrict__ csr_src,
                            int* __restrict__ csr_dst) {
    int e = blockIdx.x * blockDim.x + threadIdx.x;
    if (e < E) {
        int d = dst[e];
        int p = atomicAdd(&cur[d], 1);
        csr_src[p] = src[e];
        csr_dst[p] = d;
    }
}

// ---------------------------------------------------------------------------
// fp32 GEMM fused with attention scalars; Y written as bf16.
// SPLIT=true: X is virtual concat of X0 (rows<split) and X1.
// ---------------------------------------------------------------------------
template <int H, int C, bool SPLIT>
__global__ __launch_bounds__(256) void gemm_att_kernel(const float* __restrict__ X0,
                                                       const float* __restrict__ X1, int split,
                                                       const float* __restrict__ W,
                                                       const float* __restrict__ att_s,
                                                       const float* __restrict__ att_d,
                                                       unsigned short* __restrict__ Yb,
                                                       float* __restrict__ a_s,
                                                       float* __restrict__ a_d, int N) {
    __shared__ float xs[64][128];
    const int t = threadIdx.x;
    const int row0 = blockIdx.x * 64;

    for (int i = t; i < 64 * 128 / 4; i += 256) {
        int elem = i * 4;
        int r = elem / 128, c = elem % 128;
        int gr = row0 + r;
        float4 v = make_float4(0.f, 0.f, 0.f, 0.f);
        if (gr < N) {
            const float* xrow;
            if (SPLIT)
                xrow = (gr < split) ? &X0[(size_t)gr * 128] : &X1[(size_t)(gr - split) * 128];
            else
                xrow = &X0[(size_t)gr * 128];
            v = *(const float4*)&xrow[c];
        }
        *(float4*)&xs[r][c] = v;
    }
    __syncthreads();

    const int c0 = (t & 31) * 4;
    const int r0 = (t >> 5) * 8;
    float acc[8][4];
#pragma unroll
    for (int r = 0; r < 8; ++r)
#pragma unroll
        for (int j = 0; j < 4; ++j) acc[r][j] = 0.f;

    for (int k = 0; k < 128; ++k) {
        float4 w = *(const float4*)&W[k * 128 + c0];
#pragma unroll
        for (int r = 0; r < 8; ++r) {
            float xv = xs[r0 + r][k];
            acc[r][0] += xv * w.x;
            acc[r][1] += xv * w.y;
            acc[r][2] += xv * w.z;
            acc[r][3] += xv * w.w;
        }
    }

    const float4 asv = *(const float4*)&att_s[c0];
    const float4 adv = *(const float4*)&att_d[c0];
#pragma unroll
    for (int r = 0; r < 8; ++r) {
        int gr = row0 + r0 + r;
        if (gr < N) {
            ushort4 yv;
            yv.x = f2bf(acc[r][0]);
            yv.y = f2bf(acc[r][1]);
            yv.z = f2bf(acc[r][2]);
            yv.w = f2bf(acc[r][3]);
            *(ushort4*)&Yb[(size_t)gr * 128 + c0] = yv;
        }
        float ps = acc[r][0] * asv.x + acc[r][1] * asv.y + acc[r][2] * asv.z + acc[r][3] * asv.w;
        float pd = acc[r][0] * adv.x + acc[r][1] * adv.y + acc[r][2] * adv.z + acc[r][3] * adv.w;
#pragma unroll
        for (int m = 1; m < C / 4; m <<= 1) {
            ps += __shfl_xor(ps, m);
            pd += __shfl_xor(pd, m);
        }
        if ((t & (C / 4 - 1)) == 0 && gr < N) {
            int head = c0 / C;
            a_s[(size_t)gr * H + head] = ps;
            a_d[(size_t)gr * H + head] = pd;
        }
    }
}

// ---------------------------------------------------------------------------
// per-edge softmax numerator p = exp(leaky_relu(a_s[src]+a_d[dst]))
// (max-shift dropped: logits bounded small, softmax is shift-invariant)
// ---------------------------------------------------------------------------
__global__ void pk4_kernel(const int* __restrict__ csr_src, const int* __restrict__ csr_dst,
                           const float* __restrict__ a_s, const float* __restrict__ a_d,
                           float* __restrict__ pbuf, int E) {
    int i = blockIdx.x * blockDim.x + threadIdx.x;
    if (i >= E) return;
    int s = csr_src[i], d = csr_dst[i];
    const float4 as4 = *(const float4*)&a_s[(size_t)s * 4];
    const float4 ad4 = *(const float4*)&a_d[(size_t)d * 4];
    float4 o;
    float lg;
    lg = as4.x + ad4.x; lg = lg >= 0.f ? lg : NEG_SLOPE * lg; o.x = expf(lg);
    lg = as4.y + ad4.y; lg = lg >= 0.f ? lg : NEG_SLOPE * lg; o.y = expf(lg);
    lg = as4.z + ad4.z; lg = lg >= 0.f ? lg : NEG_SLOPE * lg; o.z = expf(lg);
    lg = as4.w + ad4.w; lg = lg >= 0.f ? lg : NEG_SLOPE * lg; o.w = expf(lg);
    *(float4*)&pbuf[(size_t)i * 4] = o;
}

__global__ void pk1_kernel(const int* __restrict__ csr_src, const int* __restrict__ csr_dst,
                           const float* __restrict__ a_s, const float* __restrict__ a_d,
                           float* __restrict__ pbuf, int E) {
    int i = blockIdx.x * blockDim.x + threadIdx.x;
    if (i >= E) return;
    float lg = a_s[csr_src[i]] + a_d[csr_dst[i]];
    lg = lg >= 0.f ? lg : NEG_SLOPE * lg;
    pbuf[i] = expf(lg);
}

// ---------------------------------------------------------------------------
// aggregation + bias + ELU + residual + LayerNorm.  One node per 128-thr block.
// h rows are bf16 (256B); p precomputed.  g = t>>5 edge group, lane = channel/4.
// ---------------------------------------------------------------------------
template <int H, bool RES>
__global__ __launch_bounds__(128) void agg_kernel(const unsigned short* __restrict__ hb,
                                                  const float* __restrict__ pbuf,
                                                  const int* __restrict__ off,
                                                  const int* __restrict__ csr_src,
                                                  const float* __restrict__ xprev,
                                                  const float* __restrict__ bias,
                                                  const float* __restrict__ ln_g,
                                                  const float* __restrict__ ln_b,
                                                  float* __restrict__ xout) {
    const int n = blockIdx.x;
    const int t = threadIdx.x;   // 0..127
    const int lane = t & 31;
    const int g = t >> 5;        // 0..3
    const int c4 = lane * 4;
    const int head = (lane * H) >> 5;
    const int base = off[n];
    const int deg = off[n + 1] - base;

    __shared__ float red4[4][32][4];
    __shared__ float redp[4][32];
    __shared__ float ws1[2], ws2[2];

    float ax = 0.f, ay = 0.f, az = 0.f, aw = 0.f;
    float psum = 0.f;

#define AGG_BODY(EE)                                                         \
    {                                                                        \
        int s_ = csr_src[base + (EE)];                                       \
        float p_ = pbuf[(size_t)(base + (EE)) * H + head];                   \
        const ushort4 hv_ = *(const ushort4*)&hb[(size_t)s_ * 128 + c4];     \
        psum += p_;                                                          \
        ax += p_ * bf2f(hv_.x); ay += p_ * bf2f(hv_.y);                      \
        az += p_ * bf2f(hv_.z); aw += p_ * bf2f(hv_.w);                      \
    }

    int e = g;
    for (; e + 4 < deg; e += 8) {
        AGG_BODY(e);
        AGG_BODY(e + 4);
    }
    if (e < deg) AGG_BODY(e);
#undef AGG_BODY

    red4[g][lane][0] = ax;
    red4[g][lane][1] = ay;
    red4[g][lane][2] = az;
    red4[g][lane][3] = aw;
    redp[g][lane] = psum;
    __syncthreads();

    // thread t owns channel t: q = lane index holding it, j = element
    const int q = t >> 2, j = t & 3;
    float sum = red4[0][q][j] + red4[1][q][j] + red4[2][q][j] + red4[3][q][j];
    float ps = redp[0][q] + redp[1][q] + redp[2][q] + redp[3][q];
    float acc = sum / (ps + 1e-16f) + bias[t];
    acc = acc > 0.f ? acc : (expf(acc) - 1.0f);
    if (RES) acc += xprev[(size_t)n * 128 + t];

    // LayerNorm: one-pass sum / sum-of-squares, shfl within wave + LDS combine
    float s1 = acc, s2 = acc * acc;
#pragma unroll
    for (int m = 1; m < 64; m <<= 1) {
        s1 += __shfl_xor(s1, m);
        s2 += __shfl_xor(s2, m);
    }
    if ((t & 63) == 0) {
        ws1[t >> 6] = s1;
        ws2[t >> 6] = s2;
    }
    __syncthreads();
    s1 = ws1[0] + ws1[1];
    s2 = ws2[0] + ws2[1];
    float mu = s1 * (1.0f / 128.0f);
    float var = s2 * (1.0f / 128.0f) - mu * mu;
    float y = (acc - mu) * rsqrtf(var + 1e-5f) * ln_g[t] + ln_b[t];
    xout[(size_t)n * 128 + t] = y;
}

// ---------------------------------------------------------------------------
// fused prediction MLP: 16 rows per 128-thread block
// ---------------------------------------------------------------------------
__global__ __launch_bounds__(128) void mlp_kernel(const float* __restrict__ x,
                                                  const int* __restrict__ uidx,
                                                  const int* __restrict__ vidx, int num_users,
                                                  const float* __restrict__ mw1,
                                                  const float* __restrict__ mb1,
                                                  const float* __restrict__ mw2,
                                                  const float* __restrict__ mb2,
                                                  const float* __restrict__ mw3,
                                                  const float* __restrict__ mb3,
                                                  float* __restrict__ out, int B) {
    const int R = 16;
    __shared__ float comb[R][256];
    __shared__ float h1s[R][128];
    __shared__ float h2s[R][64];
    int t = threadIdx.x;
    int b0 = blockIdx.x * R;

    for (int r = 0; r < R; ++r) {
        int b = b0 + r;
        if (b < B) {
            int u = uidx[b];
            int v = vidx[b] + num_users;
            comb[r][t] = x[(size_t)u * 128 + t];
            comb[r][128 + t] = x[(size_t)v * 128 + t];
        } else {
            comb[r][t] = 0.f;
            comb[r][128 + t] = 0.f;
        }
    }
    __syncthreads();

    {
        float acc[R];
#pragma unroll
        for (int r = 0; r < R; ++r) acc[r] = mb1[t];
        for (int k = 0; k < 256; ++k) {
            float w = mw1[k * 128 + t];
#pragma unroll
            for (int r = 0; r < R; ++r) acc[r] += comb[r][k] * w;
        }
#pragma unroll
        for (int r = 0; r < R; ++r) h1s[r][t] = fmaxf(acc[r], 0.f);
    }
    __syncthreads();

    if (t < 64) {
        float acc[R];
#pragma unroll
        for (int r = 0; r < R; ++r) acc[r] = mb2[t];
        for (int k = 0; k < 128; ++k) {
            float w = mw2[k * 64 + t];
#pragma unroll
            for (int r = 0; r < R; ++r) acc[r] += h1s[r][k] * w;
        }
#pragma unroll
        for (int r = 0; r < R; ++r) h2s[r][t] = fmaxf(acc[r], 0.f);
    }
    __syncthreads();

    if (t < R) {
        int b = b0 + t;
        if (b < B) {
            float s = mb3[0];
#pragma unroll
            for (int k = 0; k < 64; ++k) s += h2s[t][k] * mw3[k];
            out[b] = 1.0f / (1.0f + expf(-s));
        }
    }
}

// ---------------------------------------------------------------------------
// launcher
// ---------------------------------------------------------------------------
extern "C" void kernel_launch(void* const* d_in, const int* in_sizes, int n_in,
                              void* d_out, int out_size, void* d_ws, size_t ws_size,
                              hipStream_t stream) {
    const int* uidx = (const int*)d_in[0];
    const int* vidx = (const int*)d_in[1];
    const int* eidx = (const int*)d_in[2];
    const float* utab = (const float*)d_in[3];
    const float* itab = (const float*)d_in[4];
    const float* W0 = (const float*)d_in[5];
    const float* as0 = (const float*)d_in[6];
    const float* ad0 = (const float*)d_in[7];
    const float* bb0 = (const float*)d_in[8];
    const float* W1 = (const float*)d_in[9];
    const float* as1 = (const float*)d_in[10];
    const float* ad1 = (const float*)d_in[11];
    const float* bb1 = (const float*)d_in[12];
    const float* W2 = (const float*)d_in[13];
    const float* as2 = (const float*)d_in[14];
    const float* ad2 = (const float*)d_in[15];
    const float* bb2 = (const float*)d_in[16];
    const float* ln_g = (const float*)d_in[17];
    const float* ln_b = (const float*)d_in[18];
    const float* mw1 = (const float*)d_in[19];
    const float* mb1 = (const float*)d_in[20];
    const float* mw2 = (const float*)d_in[21];
    const float* mb2 = (const float*)d_in[22];
    const float* mw3 = (const float*)d_in[23];
    const float* mb3 = (const float*)d_in[24];

    const int B = in_sizes[0];
    const int E = in_sizes[2] / 2;
    const int num_users = in_sizes[3] / D128;
    const int num_items = in_sizes[4] / D128;
    const int N = num_users + num_items;
    const int* esrc = eidx;
    const int* edst = eidx + E;

    size_t wsoff = 0;
    auto alloc = [&](size_t bytes) {
        void* p = (char*)d_ws + wsoff;
        wsoff += (bytes + 255) & ~(size_t)255;
        return p;
    };
    float* bufA = (float*)alloc((size_t)N * 128 * 4);
    float* bufB = (float*)alloc((size_t)N * 128 * 4);
    unsigned short* hb = (unsigned short*)alloc((size_t)N * 128 * 2);
    float* aS = (float*)alloc((size_t)N * 4 * 4);
    float* aD = (float*)alloc((size_t)N * 4 * 4);
    float* pbuf = (float*)alloc((size_t)E * 4 * 4);
    int* cnt = (int*)alloc((size_t)(N + 1) * 4);
    int* off = (int*)alloc((size_t)(N + 1) * 4);
    int* cur = (int*)alloc((size_t)(N + 1) * 4);
    int* csr_src = (int*)alloc((size_t)E * 4);
    int* csr_dst = (int*)alloc((size_t)E * 4);
    int* partials = (int*)alloc(64 * 4);
    int* pp = (int*)alloc(64 * 4);
    (void)ws_size;

    // CSR by dst (hierarchical scan)
    const int NB = (N + SCAN_CHUNK - 1) / SCAN_CHUNK;
    zero_int_kernel<<<(N + 255) / 256, 256, 0, stream>>>(cnt, N);
    count_kernel<<<(E + 255) / 256, 256, 0, stream>>>(edst, E, cnt);
    scan_local_kernel<<<NB, SB, 0, stream>>>(cnt, off, partials, N);
    scan_partials_kernel<<<1, 64, 0, stream>>>(partials, pp, NB, off, N);
    scan_add_kernel<<<(N + 255) / 256, 256, 0, stream>>>(off, cur, pp, N);
    fill_kernel<<<(E + 255) / 256, 256, 0, stream>>>(esrc, edst, E, cur, csr_src, csr_dst);

    const int gemm_grid = (N + 63) / 64;
    const int egrid = (E + 255) / 256;

    // ---- layer 0 (H=4, C=32, no residual; X = virtual concat of tables) ----
    gemm_att_kernel<4, 32, true><<<gemm_grid, 256, 0, stream>>>(utab, itab, num_users, W0, as0,
                                                                ad0, hb, aS, aD, N);
    pk4_kernel<<<egrid, 256, 0, stream>>>(csr_src, csr_dst, aS, aD, pbuf, E);
    agg_kernel<4, false><<<N, 128, 0, stream>>>(hb, pbuf, off, csr_src, nullptr, bb0, ln_g,
                                                ln_b, bufB);
    // ---- layer 1 (H=4, residual) ----
    gemm_att_kernel<4, 32, false><<<gemm_grid, 256, 0, stream>>>(bufB, nullptr, 0, W1, as1, ad1,
                                                                 hb, aS, aD, N);
    pk4_kernel<<<egrid, 256, 0, stream>>>(csr_src, csr_dst, aS, aD, pbuf, E);
    agg_kernel<4, true><<<N, 128, 0, stream>>>(hb, pbuf, off, csr_src, bufB, bb1, ln_g, ln_b,
                                               bufA);
    // ---- layer 2 (H=1, residual) ----
    gemm_att_kernel<1, 128, false><<<gemm_grid, 256, 0, stream>>>(bufA, nullptr, 0, W2, as2,
                                                                  ad2, hb, aS, aD, N);
    pk1_kernel<<<egrid, 256, 0, stream>>>(csr_src, csr_dst, aS, aD, pbuf, E);
    agg_kernel<1, true><<<N, 128, 0, stream>>>(hb, pbuf, off, csr_src, bufA, bb2, ln_g, ln_b,
                                               bufB);

    // ---- prediction MLP ----
    mlp_kernel<<<(B + 15) / 16, 128, 0, stream>>>(bufB, uidx, vidx, num_users, mw1, mb1, mw2,
                                                  mb2, mw3, mb3, (float*)d_out, B);
}

// Round 5
// 397.260 us; speedup vs baseline: 1.9635x; 1.0091x over previous
//
#include <hip/hip_runtime.h>
#include <hip/hip_bf16.h>

#define D128 128
#define NEG_SLOPE 0.2f

__device__ inline float bf2f(unsigned short u) {
    return __uint_as_float(((unsigned)u) << 16);
}
__device__ inline unsigned short f2bf(float f) {  // RTNE
    unsigned u = __float_as_uint(f);
    unsigned r = (u + 0x7fffu + ((u >> 16) & 1u)) >> 16;
    return (unsigned short)r;
}

// ---------------------------------------------------------------------------
// CSR build
// ---------------------------------------------------------------------------
__global__ void zero_int_kernel(int* __restrict__ p, int n) {
    int i = blockIdx.x * blockDim.x + threadIdx.x;
    if (i < n) p[i] = 0;
}

__global__ void count_kernel(const int* __restrict__ dst, int E, int* __restrict__ cnt) {
    int e = blockIdx.x * blockDim.x + threadIdx.x;
    if (e < E) atomicAdd(&cnt[dst[e]], 1);
}

#define SB 256
#define SCAN_CHUNK 2048  // SB * 8

__global__ __launch_bounds__(SB) void scan_local_kernel(const int* __restrict__ cnt,
                                                        int* __restrict__ off,
                                                        int* __restrict__ partials, int N) {
    __shared__ int lds[SB];
    const int b = blockIdx.x;
    const int t = threadIdx.x;
    const int base = b * SCAN_CHUNK + t * 8;
    int v[8];
    int s = 0;
#pragma unroll
    for (int j = 0; j < 8; ++j) {
        int i = base + j;
        v[j] = (i < N) ? cnt[i] : 0;
        s += v[j];
    }
    lds[t] = s;
    __syncthreads();
    for (int d = 1; d < SB; d <<= 1) {
        int y = (t >= d) ? lds[t - d] : 0;
        __syncthreads();
        lds[t] += y;
        __syncthreads();
    }
    int pref = lds[t] - s;
#pragma unroll
    for (int j = 0; j < 8; ++j) {
        int i = base + j;
        if (i < N) off[i] = pref;
        pref += v[j];
    }
    if (t == SB - 1) partials[b] = lds[t];
}

__global__ __launch_bounds__(64) void scan_partials_kernel(int* __restrict__ partials,
                                                           int* __restrict__ pp, int NB,
                                                           int* __restrict__ off, int N) {
    __shared__ int lds[64];
    int t = threadIdx.x;
    int v = (t < NB) ? partials[t] : 0;
    lds[t] = v;
    __syncthreads();
    for (int d = 1; d < 64; d <<= 1) {
        int y = (t >= d) ? lds[t - d] : 0;
        __syncthreads();
        lds[t] += y;
        __syncthreads();
    }
    pp[t] = lds[t] - v;
    if (t == 63) off[N] = lds[63];
}

__global__ void scan_add_kernel(int* __restrict__ off, int* __restrict__ cur,
                                const int* __restrict__ pp, int N) {
    int i = blockIdx.x * blockDim.x + threadIdx.x;
    if (i < N) {
        int o = off[i] + pp[i / SCAN_CHUNK];
        off[i] = o;
        cur[i] = o;
    }
}

__global__ void fill_kernel(const int* __restrict__ src, const int* __restrict__ dst, int E,
                            int* __restrict__ cur, int* __restrict__ csr_src,
                            int* __restrict__ csr_dst) {
    int e = blockIdx.x * blockDim.x + threadIdx.x;
    if (e < E) {
        int d = dst[e];
        int p = atomicAdd(&cur[d], 1);
        csr_src[p] = src[e];
        csr_dst[p] = d;
    }
}

// ---------------------------------------------------------------------------
// fp32 GEMM fused with attention scalars; Y written as bf16.
// ---------------------------------------------------------------------------
template <int H, int C, bool SPLIT>
__global__ __launch_bounds__(256) void gemm_att_kernel(const float* __restrict__ X0,
                                                       const float* __restrict__ X1, int split,
                                                       const float* __restrict__ W,
                                                       const float* __restrict__ att_s,
                                                       const float* __restrict__ att_d,
                                                       unsigned short* __restrict__ Yb,
                                                       float* __restrict__ a_s,
                                                       float* __restrict__ a_d, int N) {
    __shared__ float xs[64][128];
    const int t = threadIdx.x;
    const int row0 = blockIdx.x * 64;

    for (int i = t; i < 64 * 128 / 4; i += 256) {
        int elem = i * 4;
        int r = elem / 128, c = elem % 128;
        int gr = row0 + r;
        float4 v = make_float4(0.f, 0.f, 0.f, 0.f);
        if (gr < N) {
            const float* xrow;
            if (SPLIT)
                xrow = (gr < split) ? &X0[(size_t)gr * 128] : &X1[(size_t)(gr - split) * 128];
            else
                xrow = &X0[(size_t)gr * 128];
            v = *(const float4*)&xrow[c];
        }
        *(float4*)&xs[r][c] = v;
    }
    __syncthreads();

    const int c0 = (t & 31) * 4;
    const int r0 = (t >> 5) * 8;
    float acc[8][4];
#pragma unroll
    for (int r = 0; r < 8; ++r)
#pragma unroll
        for (int j = 0; j < 4; ++j) acc[r][j] = 0.f;

    for (int k = 0; k < 128; ++k) {
        float4 w = *(const float4*)&W[k * 128 + c0];
#pragma unroll
        for (int r = 0; r < 8; ++r) {
            float xv = xs[r0 + r][k];
            acc[r][0] += xv * w.x;
            acc[r][1] += xv * w.y;
            acc[r][2] += xv * w.z;
            acc[r][3] += xv * w.w;
        }
    }

    const float4 asv = *(const float4*)&att_s[c0];
    const float4 adv = *(const float4*)&att_d[c0];
#pragma unroll
    for (int r = 0; r < 8; ++r) {
        int gr = row0 + r0 + r;
        if (gr < N) {
            ushort4 yv;
            yv.x = f2bf(acc[r][0]);
            yv.y = f2bf(acc[r][1]);
            yv.z = f2bf(acc[r][2]);
            yv.w = f2bf(acc[r][3]);
            *(ushort4*)&Yb[(size_t)gr * 128 + c0] = yv;
        }
        float ps = acc[r][0] * asv.x + acc[r][1] * asv.y + acc[r][2] * asv.z + acc[r][3] * asv.w;
        float pd = acc[r][0] * adv.x + acc[r][1] * adv.y + acc[r][2] * adv.z + acc[r][3] * adv.w;
#pragma unroll
        for (int m = 1; m < C / 4; m <<= 1) {
            ps += __shfl_xor(ps, m);
            pd += __shfl_xor(pd, m);
        }
        if ((t & (C / 4 - 1)) == 0 && gr < N) {
            int head = c0 / C;
            a_s[(size_t)gr * H + head] = ps;
            a_d[(size_t)gr * H + head] = pd;
        }
    }
}

// ---------------------------------------------------------------------------
// per-edge softmax numerator p = exp(leaky_relu(a_s[src]+a_d[dst]))
// ---------------------------------------------------------------------------
__global__ void pk4_kernel(const int* __restrict__ csr_src, const int* __restrict__ csr_dst,
                           const float* __restrict__ a_s, const float* __restrict__ a_d,
                           float* __restrict__ pbuf, int E) {
    int i = blockIdx.x * blockDim.x + threadIdx.x;
    if (i >= E) return;
    int s = csr_src[i], d = csr_dst[i];
    const float4 as4 = *(const float4*)&a_s[(size_t)s * 4];
    const float4 ad4 = *(const float4*)&a_d[(size_t)d * 4];
    float4 o;
    float lg;
    lg = as4.x + ad4.x; lg = lg >= 0.f ? lg : NEG_SLOPE * lg; o.x = expf(lg);
    lg = as4.y + ad4.y; lg = lg >= 0.f ? lg : NEG_SLOPE * lg; o.y = expf(lg);
    lg = as4.z + ad4.z; lg = lg >= 0.f ? lg : NEG_SLOPE * lg; o.z = expf(lg);
    lg = as4.w + ad4.w; lg = lg >= 0.f ? lg : NEG_SLOPE * lg; o.w = expf(lg);
    *(float4*)&pbuf[(size_t)i * 4] = o;
}

__global__ void pk1_kernel(const int* __restrict__ csr_src, const int* __restrict__ csr_dst,
                           const float* __restrict__ a_s, const float* __restrict__ a_d,
                           float* __restrict__ pbuf, int E) {
    int i = blockIdx.x * blockDim.x + threadIdx.x;
    if (i >= E) return;
    float lg = a_s[csr_src[i]] + a_d[csr_dst[i]];
    lg = lg >= 0.f ? lg : NEG_SLOPE * lg;
    pbuf[i] = expf(lg);
}

// ---------------------------------------------------------------------------
// aggregation + bias + ELU + residual + LayerNorm.  One node per 128-thr block.
// ---------------------------------------------------------------------------
template <int H, bool RES>
__global__ __launch_bounds__(128) void agg_kernel(const unsigned short* __restrict__ hb,
                                                  const float* __restrict__ pbuf,
                                                  const int* __restrict__ off,
                                                  const int* __restrict__ csr_src,
                                                  const float* __restrict__ xprev,
                                                  const float* __restrict__ bias,
                                                  const float* __restrict__ ln_g,
                                                  const float* __restrict__ ln_b,
                                                  float* __restrict__ xout) {
    const int n = blockIdx.x;
    const int t = threadIdx.x;   // 0..127
    const int lane = t & 31;
    const int g = t >> 5;        // 0..3
    const int c4 = lane * 4;
    const int head = (lane * H) >> 5;
    const int base = off[n];
    const int deg = off[n + 1] - base;

    __shared__ float red4[4][32][4];
    __shared__ float redp[4][32];
    __shared__ float ws1[2], ws2[2];

    float ax = 0.f, ay = 0.f, az = 0.f, aw = 0.f;
    float psum = 0.f;

#define AGG_BODY(EE)                                                         \
    {                                                                        \
        int s_ = csr_src[base + (EE)];                                       \
        float p_ = pbuf[(size_t)(base + (EE)) * H + head];                   \
        const ushort4 hv_ = *(const ushort4*)&hb[(size_t)s_ * 128 + c4];     \
        psum += p_;                                                          \
        ax += p_ * bf2f(hv_.x); ay += p_ * bf2f(hv_.y);                      \
        az += p_ * bf2f(hv_.z); aw += p_ * bf2f(hv_.w);                      \
    }

    int e = g;
    for (; e + 4 < deg; e += 8) {
        AGG_BODY(e);
        AGG_BODY(e + 4);
    }
    if (e < deg) AGG_BODY(e);
#undef AGG_BODY

    red4[g][lane][0] = ax;
    red4[g][lane][1] = ay;
    red4[g][lane][2] = az;
    red4[g][lane][3] = aw;
    redp[g][lane] = psum;
    __syncthreads();

    const int q = t >> 2, j = t & 3;
    float sum = red4[0][q][j] + red4[1][q][j] + red4[2][q][j] + red4[3][q][j];
    float ps = redp[0][q] + redp[1][q] + redp[2][q] + redp[3][q];
    float acc = sum / (ps + 1e-16f) + bias[t];
    acc = acc > 0.f ? acc : (expf(acc) - 1.0f);
    if (RES) acc += xprev[(size_t)n * 128 + t];

    float s1 = acc, s2 = acc * acc;
#pragma unroll
    for (int m = 1; m < 64; m <<= 1) {
        s1 += __shfl_xor(s1, m);
        s2 += __shfl_xor(s2, m);
    }
    if ((t & 63) == 0) {
        ws1[t >> 6] = s1;
        ws2[t >> 6] = s2;
    }
    __syncthreads();
    s1 = ws1[0] + ws1[1];
    s2 = ws2[0] + ws2[1];
    float mu = s1 * (1.0f / 128.0f);
    float var = s2 * (1.0f / 128.0f) - mu * mu;
    float y = (acc - mu) * rsqrtf(var + 1e-5f) * ln_g[t] + ln_b[t];
    xout[(size_t)n * 128 + t] = y;
}

// ---------------------------------------------------------------------------
// fused prediction MLP, register-blocked: 64 rows per 256-thread block.
// L1: 256->128 (8x4 micro-tile), L2: 128->64 (8x2, k-unroll-4 b128 reads),
// L3: 64->1 (4-lane split dot + shfl reduce).  comb staged half at a time.
// ---------------------------------------------------------------------------
__global__ __launch_bounds__(256) void mlp_kernel(const float* __restrict__ x,
                                                  const int* __restrict__ uidx,
                                                  const int* __restrict__ vidx, int num_users,
                                                  const float* __restrict__ mw1,
                                                  const float* __restrict__ mb1,
                                                  const float* __restrict__ mw2,
                                                  const float* __restrict__ mb2,
                                                  const float* __restrict__ mw3,
                                                  const float* __restrict__ mb3,
                                                  float* __restrict__ out, int B) {
    __shared__ float xs[64][128];   // comb half; later reused for h2 [64][64]
    __shared__ float h1s[64][128];
    const int t = threadIdx.x;
    const int b0 = blockIdx.x * 64;

    const int c0 = (t & 31) * 4;    // layer-1 cols (0..127)
    const int r0 = (t >> 5) * 8;    // rows (0..63)

    float acc[8][4];
    const float4 bias1 = *(const float4*)&mb1[c0];
#pragma unroll
    for (int r = 0; r < 8; ++r) {
        acc[r][0] = bias1.x; acc[r][1] = bias1.y;
        acc[r][2] = bias1.z; acc[r][3] = bias1.w;
    }

    // ---- half 0: user embeddings (k = 0..127) ----
    for (int i = t; i < 64 * 32; i += 256) {
        int r = i >> 5, c = (i & 31) * 4;
        int b = b0 + r;
        float4 v = make_float4(0.f, 0.f, 0.f, 0.f);
        if (b < B) v = *(const float4*)&x[(size_t)uidx[b] * 128 + c];
        *(float4*)&xs[r][c] = v;
    }
    __syncthreads();
    for (int k = 0; k < 128; ++k) {
        float4 w = *(const float4*)&mw1[k * 128 + c0];
#pragma unroll
        for (int r = 0; r < 8; ++r) {
            float xv = xs[r0 + r][k];
            acc[r][0] += xv * w.x; acc[r][1] += xv * w.y;
            acc[r][2] += xv * w.z; acc[r][3] += xv * w.w;
        }
    }
    __syncthreads();

    // ---- half 1: item embeddings (k = 128..255) ----
    for (int i = t; i < 64 * 32; i += 256) {
        int r = i >> 5, c = (i & 31) * 4;
        int b = b0 + r;
        float4 v = make_float4(0.f, 0.f, 0.f, 0.f);
        if (b < B) v = *(const float4*)&x[(size_t)(vidx[b] + num_users) * 128 + c];
        *(float4*)&xs[r][c] = v;
    }
    __syncthreads();
    for (int k = 0; k < 128; ++k) {
        float4 w = *(const float4*)&mw1[(128 + k) * 128 + c0];
#pragma unroll
        for (int r = 0; r < 8; ++r) {
            float xv = xs[r0 + r][k];
            acc[r][0] += xv * w.x; acc[r][1] += xv * w.y;
            acc[r][2] += xv * w.z; acc[r][3] += xv * w.w;
        }
    }

    // relu -> h1s
#pragma unroll
    for (int r = 0; r < 8; ++r) {
        float4 h;
        h.x = fmaxf(acc[r][0], 0.f); h.y = fmaxf(acc[r][1], 0.f);
        h.z = fmaxf(acc[r][2], 0.f); h.w = fmaxf(acc[r][3], 0.f);
        *(float4*)&h1s[r0 + r][c0] = h;
    }
    __syncthreads();

    // ---- layer 2: 128 -> 64, cols c2..c2+1, rows r0..r0+7 ----
    const int c2 = (t & 31) * 2;
    float acc2[8][2];
    const float b2x = mb2[c2], b2y = mb2[c2 + 1];
#pragma unroll
    for (int r = 0; r < 8; ++r) { acc2[r][0] = b2x; acc2[r][1] = b2y; }

    for (int k = 0; k < 128; k += 4) {
        float2 w0 = *(const float2*)&mw2[(k + 0) * 64 + c2];
        float2 w1 = *(const float2*)&mw2[(k + 1) * 64 + c2];
        float2 w2v = *(const float2*)&mw2[(k + 2) * 64 + c2];
        float2 w3 = *(const float2*)&mw2[(k + 3) * 64 + c2];
#pragma unroll
        for (int r = 0; r < 8; ++r) {
            float4 hv = *(const float4*)&h1s[r0 + r][k];
            acc2[r][0] += hv.x * w0.x + hv.y * w1.x + hv.z * w2v.x + hv.w * w3.x;
            acc2[r][1] += hv.x * w0.y + hv.y * w1.y + hv.z * w2v.y + hv.w * w3.y;
        }
    }

    // relu -> h2 (overlay on xs)
    float* h2p = &xs[0][0];  // [64][64]
#pragma unroll
    for (int r = 0; r < 8; ++r) {
        float2 h;
        h.x = fmaxf(acc2[r][0], 0.f);
        h.y = fmaxf(acc2[r][1], 0.f);
        *(float2*)&h2p[(r0 + r) * 64 + c2] = h;
    }
    __syncthreads();

    // ---- layer 3: 64 -> 1; 4 threads per row ----
    {
        const int row = t >> 2, q = t & 3;
        float s = 0.f;
        const float* hrow = &h2p[row * 64 + q * 16];
        const float* wrow = &mw3[q * 16];
#pragma unroll
        for (int kk = 0; kk < 16; ++kk) s += hrow[kk] * wrow[kk];
        s += __shfl_xor(s, 1);
        s += __shfl_xor(s, 2);
        int b = b0 + row;
        if (q == 0 && b < B) out[b] = 1.0f / (1.0f + expf(-(s + mb3[0])));
    }
}

// ---------------------------------------------------------------------------
// launcher
// ---------------------------------------------------------------------------
extern "C" void kernel_launch(void* const* d_in, const int* in_sizes, int n_in,
                              void* d_out, int out_size, void* d_ws, size_t ws_size,
                              hipStream_t stream) {
    const int* uidx = (const int*)d_in[0];
    const int* vidx = (const int*)d_in[1];
    const int* eidx = (const int*)d_in[2];
    const float* utab = (const float*)d_in[3];
    const float* itab = (const float*)d_in[4];
    const float* W0 = (const float*)d_in[5];
    const float* as0 = (const float*)d_in[6];
    const float* ad0 = (const float*)d_in[7];
    const float* bb0 = (const float*)d_in[8];
    const float* W1 = (const float*)d_in[9];
    const float* as1 = (const float*)d_in[10];
    const float* ad1 = (const float*)d_in[11];
    const float* bb1 = (const float*)d_in[12];
    const float* W2 = (const float*)d_in[13];
    const float* as2 = (const float*)d_in[14];
    const float* ad2 = (const float*)d_in[15];
    const float* bb2 = (const float*)d_in[16];
    const float* ln_g = (const float*)d_in[17];
    const float* ln_b = (const float*)d_in[18];
    const float* mw1 = (const float*)d_in[19];
    const float* mb1 = (const float*)d_in[20];
    const float* mw2 = (const float*)d_in[21];
    const float* mb2 = (const float*)d_in[22];
    const float* mw3 = (const float*)d_in[23];
    const float* mb3 = (const float*)d_in[24];

    const int B = in_sizes[0];
    const int E = in_sizes[2] / 2;
    const int num_users = in_sizes[3] / D128;
    const int num_items = in_sizes[4] / D128;
    const int N = num_users + num_items;
    const int* esrc = eidx;
    const int* edst = eidx + E;

    size_t wsoff = 0;
    auto alloc = [&](size_t bytes) {
        void* p = (char*)d_ws + wsoff;
        wsoff += (bytes + 255) & ~(size_t)255;
        return p;
    };
    float* bufA = (float*)alloc((size_t)N * 128 * 4);
    float* bufB = (float*)alloc((size_t)N * 128 * 4);
    unsigned short* hb = (unsigned short*)alloc((size_t)N * 128 * 2);
    float* aS = (float*)alloc((size_t)N * 4 * 4);
    float* aD = (float*)alloc((size_t)N * 4 * 4);
    float* pbuf = (float*)alloc((size_t)E * 4 * 4);
    int* cnt = (int*)alloc((size_t)(N + 1) * 4);
    int* off = (int*)alloc((size_t)(N + 1) * 4);
    int* cur = (int*)alloc((size_t)(N + 1) * 4);
    int* csr_src = (int*)alloc((size_t)E * 4);
    int* csr_dst = (int*)alloc((size_t)E * 4);
    int* partials = (int*)alloc(64 * 4);
    int* pp = (int*)alloc(64 * 4);
    (void)ws_size;

    const int NB = (N + SCAN_CHUNK - 1) / SCAN_CHUNK;
    zero_int_kernel<<<(N + 255) / 256, 256, 0, stream>>>(cnt, N);
    count_kernel<<<(E + 255) / 256, 256, 0, stream>>>(edst, E, cnt);
    scan_local_kernel<<<NB, SB, 0, stream>>>(cnt, off, partials, N);
    scan_partials_kernel<<<1, 64, 0, stream>>>(partials, pp, NB, off, N);
    scan_add_kernel<<<(N + 255) / 256, 256, 0, stream>>>(off, cur, pp, N);
    fill_kernel<<<(E + 255) / 256, 256, 0, stream>>>(esrc, edst, E, cur, csr_src, csr_dst);

    const int gemm_grid = (N + 63) / 64;
    const int egrid = (E + 255) / 256;

    // ---- layer 0 (H=4, C=32, no residual; X = virtual concat of tables) ----
    gemm_att_kernel<4, 32, true><<<gemm_grid, 256, 0, stream>>>(utab, itab, num_users, W0, as0,
                                                                ad0, hb, aS, aD, N);
    pk4_kernel<<<egrid, 256, 0, stream>>>(csr_src, csr_dst, aS, aD, pbuf, E);
    agg_kernel<4, false><<<N, 128, 0, stream>>>(hb, pbuf, off, csr_src, nullptr, bb0, ln_g,
                                                ln_b, bufB);
    // ---- layer 1 (H=4, residual) ----
    gemm_att_kernel<4, 32, false><<<gemm_grid, 256, 0, stream>>>(bufB, nullptr, 0, W1, as1, ad1,
                                                                 hb, aS, aD, N);
    pk4_kernel<<<egrid, 256, 0, stream>>>(csr_src, csr_dst, aS, aD, pbuf, E);
    agg_kernel<4, true><<<N, 128, 0, stream>>>(hb, pbuf, off, csr_src, bufB, bb1, ln_g, ln_b,
                                               bufA);
    // ---- layer 2 (H=1, residual) ----
    gemm_att_kernel<1, 128, false><<<gemm_grid, 256, 0, stream>>>(bufA, nullptr, 0, W2, as2,
                                                                  ad2, hb, aS, aD, N);
    pk1_kernel<<<egrid, 256, 0, stream>>>(csr_src, csr_dst, aS, aD, pbuf, E);
    agg_kernel<1, true><<<N, 128, 0, stream>>>(hb, pbuf, off, csr_src, bufA, bb2, ln_g, ln_b,
                                               bufB);

    // ---- prediction MLP ----
    mlp_kernel<<<(B + 63) / 64, 256, 0, stream>>>(bufB, uidx, vidx, num_users, mw1, mb1, mw2,
                                                  mb2, mw3, mb3, (float*)d_out, B);
}

// Round 6
// 363.326 us; speedup vs baseline: 2.1469x; 1.0934x over previous
//
#include <hip/hip_runtime.h>
#include <hip/hip_bf16.h>

#define D128 128
#define NEG_SLOPE 0.2f

__device__ inline float bf2f(unsigned short u) {
    return __uint_as_float(((unsigned)u) << 16);
}
__device__ inline unsigned short f2bf(float f) {  // RTNE
    unsigned u = __float_as_uint(f);
    unsigned r = (u + 0x7fffu + ((u >> 16) & 1u)) >> 16;
    return (unsigned short)r;
}

// ---------------------------------------------------------------------------
// CSR build
// ---------------------------------------------------------------------------
__global__ void zero_int_kernel(int* __restrict__ p, int n) {
    int i = blockIdx.x * blockDim.x + threadIdx.x;
    if (i < n) p[i] = 0;
}

__global__ void count_kernel(const int* __restrict__ dst, int E, int* __restrict__ cnt) {
    int e = blockIdx.x * blockDim.x + threadIdx.x;
    if (e < E) atomicAdd(&cnt[dst[e]], 1);
}

#define SB 256
#define SCAN_CHUNK 2048  // SB * 8

__global__ __launch_bounds__(SB) void scan_local_kernel(const int* __restrict__ cnt,
                                                        int* __restrict__ off,
                                                        int* __restrict__ partials, int N) {
    __shared__ int lds[SB];
    const int b = blockIdx.x;
    const int t = threadIdx.x;
    const int base = b * SCAN_CHUNK + t * 8;
    int v[8];
    int s = 0;
#pragma unroll
    for (int j = 0; j < 8; ++j) {
        int i = base + j;
        v[j] = (i < N) ? cnt[i] : 0;
        s += v[j];
    }
    lds[t] = s;
    __syncthreads();
    for (int d = 1; d < SB; d <<= 1) {
        int y = (t >= d) ? lds[t - d] : 0;
        __syncthreads();
        lds[t] += y;
        __syncthreads();
    }
    int pref = lds[t] - s;
#pragma unroll
    for (int j = 0; j < 8; ++j) {
        int i = base + j;
        if (i < N) off[i] = pref;
        pref += v[j];
    }
    if (t == SB - 1) partials[b] = lds[t];
}

__global__ __launch_bounds__(64) void scan_partials_kernel(int* __restrict__ partials,
                                                           int* __restrict__ pp, int NB,
                                                           int* __restrict__ off, int N) {
    __shared__ int lds[64];
    int t = threadIdx.x;
    int v = (t < NB) ? partials[t] : 0;
    lds[t] = v;
    __syncthreads();
    for (int d = 1; d < 64; d <<= 1) {
        int y = (t >= d) ? lds[t - d] : 0;
        __syncthreads();
        lds[t] += y;
        __syncthreads();
    }
    pp[t] = lds[t] - v;
    if (t == 63) off[N] = lds[63];
}

__global__ void scan_add_kernel(int* __restrict__ off, int* __restrict__ cur,
                                const int* __restrict__ pp, int N) {
    int i = blockIdx.x * blockDim.x + threadIdx.x;
    if (i < N) {
        int o = off[i] + pp[i / SCAN_CHUNK];
        off[i] = o;
        cur[i] = o;
    }
}

__global__ void fill_kernel(const int* __restrict__ src, const int* __restrict__ dst, int E,
                            int* __restrict__ cur, int* __restrict__ csr_src,
                            int* __restrict__ csr_dst) {
    int e = blockIdx.x * blockDim.x + threadIdx.x;
    if (e < E) {
        int d = dst[e];
        int p = atomicAdd(&cur[d], 1);
        csr_src[p] = src[e];
        csr_dst[p] = d;
    }
}

// ---------------------------------------------------------------------------
// fp32 GEMM fused with attention scalars; Y written as bf16.
// ---------------------------------------------------------------------------
template <int H, int C, bool SPLIT>
__global__ __launch_bounds__(256) void gemm_att_kernel(const float* __restrict__ X0,
                                                       const float* __restrict__ X1, int split,
                                                       const float* __restrict__ W,
                                                       const float* __restrict__ att_s,
                                                       const float* __restrict__ att_d,
                                                       unsigned short* __restrict__ Yb,
                                                       float* __restrict__ a_s,
                                                       float* __restrict__ a_d, int N) {
    __shared__ float xs[64][128];
    const int t = threadIdx.x;
    const int row0 = blockIdx.x * 64;

    for (int i = t; i < 64 * 128 / 4; i += 256) {
        int elem = i * 4;
        int r = elem / 128, c = elem % 128;
        int gr = row0 + r;
        float4 v = make_float4(0.f, 0.f, 0.f, 0.f);
        if (gr < N) {
            const float* xrow;
            if (SPLIT)
                xrow = (gr < split) ? &X0[(size_t)gr * 128] : &X1[(size_t)(gr - split) * 128];
            else
                xrow = &X0[(size_t)gr * 128];
            v = *(const float4*)&xrow[c];
        }
        *(float4*)&xs[r][c] = v;
    }
    __syncthreads();

    const int c0 = (t & 31) * 4;
    const int r0 = (t >> 5) * 8;
    float acc[8][4];
#pragma unroll
    for (int r = 0; r < 8; ++r)
#pragma unroll
        for (int j = 0; j < 4; ++j) acc[r][j] = 0.f;

    for (int k = 0; k < 128; ++k) {
        float4 w = *(const float4*)&W[k * 128 + c0];
#pragma unroll
        for (int r = 0; r < 8; ++r) {
            float xv = xs[r0 + r][k];
            acc[r][0] += xv * w.x;
            acc[r][1] += xv * w.y;
            acc[r][2] += xv * w.z;
            acc[r][3] += xv * w.w;
        }
    }

    const float4 asv = *(const float4*)&att_s[c0];
    const float4 adv = *(const float4*)&att_d[c0];
#pragma unroll
    for (int r = 0; r < 8; ++r) {
        int gr = row0 + r0 + r;
        if (gr < N) {
            ushort4 yv;
            yv.x = f2bf(acc[r][0]);
            yv.y = f2bf(acc[r][1]);
            yv.z = f2bf(acc[r][2]);
            yv.w = f2bf(acc[r][3]);
            *(ushort4*)&Yb[(size_t)gr * 128 + c0] = yv;
        }
        float ps = acc[r][0] * asv.x + acc[r][1] * asv.y + acc[r][2] * asv.z + acc[r][3] * asv.w;
        float pd = acc[r][0] * adv.x + acc[r][1] * adv.y + acc[r][2] * adv.z + acc[r][3] * adv.w;
#pragma unroll
        for (int m = 1; m < C / 4; m <<= 1) {
            ps += __shfl_xor(ps, m);
            pd += __shfl_xor(pd, m);
        }
        if ((t & (C / 4 - 1)) == 0 && gr < N) {
            int head = c0 / C;
            a_s[(size_t)gr * H + head] = ps;
            a_d[(size_t)gr * H + head] = pd;
        }
    }
}

// ---------------------------------------------------------------------------
// per-edge softmax numerator p = exp(leaky_relu(a_s[src]+a_d[dst]))
// ---------------------------------------------------------------------------
__global__ void pk4_kernel(const int* __restrict__ csr_src, const int* __restrict__ csr_dst,
                           const float* __restrict__ a_s, const float* __restrict__ a_d,
                           float* __restrict__ pbuf, int E) {
    int i = blockIdx.x * blockDim.x + threadIdx.x;
    if (i >= E) return;
    int s = csr_src[i], d = csr_dst[i];
    const float4 as4 = *(const float4*)&a_s[(size_t)s * 4];
    const float4 ad4 = *(const float4*)&a_d[(size_t)d * 4];
    float4 o;
    float lg;
    lg = as4.x + ad4.x; lg = lg >= 0.f ? lg : NEG_SLOPE * lg; o.x = expf(lg);
    lg = as4.y + ad4.y; lg = lg >= 0.f ? lg : NEG_SLOPE * lg; o.y = expf(lg);
    lg = as4.z + ad4.z; lg = lg >= 0.f ? lg : NEG_SLOPE * lg; o.z = expf(lg);
    lg = as4.w + ad4.w; lg = lg >= 0.f ? lg : NEG_SLOPE * lg; o.w = expf(lg);
    *(float4*)&pbuf[(size_t)i * 4] = o;
}

__global__ void pk1_kernel(const int* __restrict__ csr_src, const int* __restrict__ csr_dst,
                           const float* __restrict__ a_s, const float* __restrict__ a_d,
                           float* __restrict__ pbuf, int E) {
    int i = blockIdx.x * blockDim.x + threadIdx.x;
    if (i >= E) return;
    float lg = a_s[csr_src[i]] + a_d[csr_dst[i]];
    lg = lg >= 0.f ? lg : NEG_SLOPE * lg;
    pbuf[i] = expf(lg);
}

// ---------------------------------------------------------------------------
// aggregation + bias + ELU + residual + LayerNorm.
// ONE WAVE PER NODE: lane = 2 channels, edges 2-at-a-time (dual load chains),
// LayerNorm via shfl only.  No LDS, no barriers.  4 nodes / 256-thr block.
// ---------------------------------------------------------------------------
template <int H, bool RES>
__global__ __launch_bounds__(256) void agg_kernel(const unsigned short* __restrict__ hb,
                                                  const float* __restrict__ pbuf,
                                                  const int* __restrict__ off,
                                                  const int* __restrict__ csr_src,
                                                  const float* __restrict__ xprev,
                                                  const float* __restrict__ bias,
                                                  const float* __restrict__ ln_g,
                                                  const float* __restrict__ ln_b,
                                                  float* __restrict__ xout, int N) {
    const int lane = threadIdx.x & 63;
    const int n = blockIdx.x * 4 + (threadIdx.x >> 6);
    if (n >= N) return;
    const int c2 = lane * 2;
    const int head = (c2 * H) >> 7;  // c2 / (128/H)
    const int base = off[n];
    const int deg = off[n + 1] - base;

    float a0 = 0.f, a1 = 0.f, ps0 = 0.f;
    float b0 = 0.f, b1 = 0.f, ps1 = 0.f;
    int e = 0;
    for (; e + 1 < deg; e += 2) {
        int s0 = csr_src[base + e];
        int s1 = csr_src[base + e + 1];
        float p0 = pbuf[(size_t)(base + e) * H + head];
        float p1 = pbuf[(size_t)(base + e + 1) * H + head];
        unsigned hv0 = *(const unsigned*)&hb[((size_t)s0 << 7) + c2];
        unsigned hv1 = *(const unsigned*)&hb[((size_t)s1 << 7) + c2];
        ps0 += p0;
        ps1 += p1;
        a0 = fmaf(p0, bf2f((unsigned short)hv0), a0);
        a1 = fmaf(p0, bf2f((unsigned short)(hv0 >> 16)), a1);
        b0 = fmaf(p1, bf2f((unsigned short)hv1), b0);
        b1 = fmaf(p1, bf2f((unsigned short)(hv1 >> 16)), b1);
    }
    if (e < deg) {
        int s0 = csr_src[base + e];
        float p0 = pbuf[(size_t)(base + e) * H + head];
        unsigned hv0 = *(const unsigned*)&hb[((size_t)s0 << 7) + c2];
        ps0 += p0;
        a0 = fmaf(p0, bf2f((unsigned short)hv0), a0);
        a1 = fmaf(p0, bf2f((unsigned short)(hv0 >> 16)), a1);
    }
    a0 += b0;
    a1 += b1;
    float psum = ps0 + ps1;

    float inv = 1.0f / (psum + 1e-16f);
    float acc0 = a0 * inv + bias[c2];
    float acc1 = a1 * inv + bias[c2 + 1];
    acc0 = acc0 > 0.f ? acc0 : (expf(acc0) - 1.0f);
    acc1 = acc1 > 0.f ? acc1 : (expf(acc1) - 1.0f);
    if (RES) {
        float2 xp = *(const float2*)&xprev[((size_t)n << 7) + c2];
        acc0 += xp.x;
        acc1 += xp.y;
    }

    float s1v = acc0 + acc1;
    float s2v = acc0 * acc0 + acc1 * acc1;
#pragma unroll
    for (int m = 1; m < 64; m <<= 1) {
        s1v += __shfl_xor(s1v, m);
        s2v += __shfl_xor(s2v, m);
    }
    float mu = s1v * (1.0f / 128.0f);
    float var = s2v * (1.0f / 128.0f) - mu * mu;
    float rstd = rsqrtf(var + 1e-5f);
    float2 o;
    o.x = (acc0 - mu) * rstd * ln_g[c2] + ln_b[c2];
    o.y = (acc1 - mu) * rstd * ln_g[c2 + 1] + ln_b[c2 + 1];
    *(float2*)&xout[((size_t)n << 7) + c2] = o;
}

// ---------------------------------------------------------------------------
// fused prediction MLP: 32 rows per 256-thread block, 8-deep weight prefetch.
// ---------------------------------------------------------------------------
__global__ __launch_bounds__(256) void mlp_kernel(const float* __restrict__ x,
                                                  const int* __restrict__ uidx,
                                                  const int* __restrict__ vidx, int num_users,
                                                  const float* __restrict__ mw1,
                                                  const float* __restrict__ mb1,
                                                  const float* __restrict__ mw2,
                                                  const float* __restrict__ mb2,
                                                  const float* __restrict__ mw3,
                                                  const float* __restrict__ mb3,
                                                  float* __restrict__ out, int B) {
    __shared__ float xs[32][128];
    __shared__ float h1s[32][128];
    __shared__ float h2s[32][66];  // padded: layer-3 reads conflict-free
    const int t = threadIdx.x;
    const int b0 = blockIdx.x * 32;
    const int c0 = (t & 31) * 4;  // cols 0..127
    const int r0 = (t >> 5) * 4;  // rows 0..31

    float acc[4][4];
    const float4 bias1 = *(const float4*)&mb1[c0];
#pragma unroll
    for (int r = 0; r < 4; ++r) {
        acc[r][0] = bias1.x; acc[r][1] = bias1.y;
        acc[r][2] = bias1.z; acc[r][3] = bias1.w;
    }

    // ---- half 0: user embeddings ----
    for (int i = t; i < 32 * 32; i += 256) {
        int r = i >> 5, c = (i & 31) * 4;
        int b = b0 + r;
        float4 v = make_float4(0.f, 0.f, 0.f, 0.f);
        if (b < B) v = *(const float4*)&x[(size_t)uidx[b] * 128 + c];
        *(float4*)&xs[r][c] = v;
    }
    __syncthreads();
    for (int k = 0; k < 128; k += 8) {
        float4 w[8];
#pragma unroll
        for (int j = 0; j < 8; ++j) w[j] = *(const float4*)&mw1[(k + j) * 128 + c0];
#pragma unroll
        for (int j = 0; j < 8; ++j)
#pragma unroll
            for (int r = 0; r < 4; ++r) {
                float xv = xs[r0 + r][k + j];
                acc[r][0] += xv * w[j].x; acc[r][1] += xv * w[j].y;
                acc[r][2] += xv * w[j].z; acc[r][3] += xv * w[j].w;
            }
    }
    __syncthreads();

    // ---- half 1: item embeddings ----
    for (int i = t; i < 32 * 32; i += 256) {
        int r = i >> 5, c = (i & 31) * 4;
        int b = b0 + r;
        float4 v = make_float4(0.f, 0.f, 0.f, 0.f);
        if (b < B) v = *(const float4*)&x[(size_t)(vidx[b] + num_users) * 128 + c];
        *(float4*)&xs[r][c] = v;
    }
    __syncthreads();
    for (int k = 0; k < 128; k += 8) {
        float4 w[8];
#pragma unroll
        for (int j = 0; j < 8; ++j) w[j] = *(const float4*)&mw1[(128 + k + j) * 128 + c0];
#pragma unroll
        for (int j = 0; j < 8; ++j)
#pragma unroll
            for (int r = 0; r < 4; ++r) {
                float xv = xs[r0 + r][k + j];
                acc[r][0] += xv * w[j].x; acc[r][1] += xv * w[j].y;
                acc[r][2] += xv * w[j].z; acc[r][3] += xv * w[j].w;
            }
    }

#pragma unroll
    for (int r = 0; r < 4; ++r) {
        float4 h;
        h.x = fmaxf(acc[r][0], 0.f); h.y = fmaxf(acc[r][1], 0.f);
        h.z = fmaxf(acc[r][2], 0.f); h.w = fmaxf(acc[r][3], 0.f);
        *(float4*)&h1s[r0 + r][c0] = h;
    }
    __syncthreads();

    // ---- layer 2: 128 -> 64 ----
    const int c2 = (t & 31) * 2;
    float acc2[4][2];
    const float b2x = mb2[c2], b2y = mb2[c2 + 1];
#pragma unroll
    for (int r = 0; r < 4; ++r) { acc2[r][0] = b2x; acc2[r][1] = b2y; }

    for (int k = 0; k < 128; k += 8) {
        float2 w[8];
#pragma unroll
        for (int j = 0; j < 8; ++j) w[j] = *(const float2*)&mw2[(k + j) * 64 + c2];
#pragma unroll
        for (int r = 0; r < 4; ++r) {
            float4 h0 = *(const float4*)&h1s[r0 + r][k];
            float4 h1 = *(const float4*)&h1s[r0 + r][k + 4];
            acc2[r][0] += h0.x * w[0].x + h0.y * w[1].x + h0.z * w[2].x + h0.w * w[3].x +
                          h1.x * w[4].x + h1.y * w[5].x + h1.z * w[6].x + h1.w * w[7].x;
            acc2[r][1] += h0.x * w[0].y + h0.y * w[1].y + h0.z * w[2].y + h0.w * w[3].y +
                          h1.x * w[4].y + h1.y * w[5].y + h1.z * w[6].y + h1.w * w[7].y;
        }
    }

#pragma unroll
    for (int r = 0; r < 4; ++r) {
        float2 h;
        h.x = fmaxf(acc2[r][0], 0.f);
        h.y = fmaxf(acc2[r][1], 0.f);
        *(float2*)&h2s[r0 + r][c2] = h;
    }
    __syncthreads();

    // ---- layer 3: 64 -> 1; 8 threads per row ----
    {
        const int row = t >> 3, q = t & 7;
        float s = 0.f;
        const float* hrow = &h2s[row][q * 8];
        const float* wrow = &mw3[q * 8];
#pragma unroll
        for (int kk = 0; kk < 8; ++kk) s += hrow[kk] * wrow[kk];
        s += __shfl_xor(s, 1);
        s += __shfl_xor(s, 2);
        s += __shfl_xor(s, 4);
        int b = b0 + row;
        if (q == 0 && b < B) out[b] = 1.0f / (1.0f + expf(-(s + mb3[0])));
    }
}

// ---------------------------------------------------------------------------
// launcher
// ---------------------------------------------------------------------------
extern "C" void kernel_launch(void* const* d_in, const int* in_sizes, int n_in,
                              void* d_out, int out_size, void* d_ws, size_t ws_size,
                              hipStream_t stream) {
    const int* uidx = (const int*)d_in[0];
    const int* vidx = (const int*)d_in[1];
    const int* eidx = (const int*)d_in[2];
    const float* utab = (const float*)d_in[3];
    const float* itab = (const float*)d_in[4];
    const float* W0 = (const float*)d_in[5];
    const float* as0 = (const float*)d_in[6];
    const float* ad0 = (const float*)d_in[7];
    const float* bb0 = (const float*)d_in[8];
    const float* W1 = (const float*)d_in[9];
    const float* as1 = (const float*)d_in[10];
    const float* ad1 = (const float*)d_in[11];
    const float* bb1 = (const float*)d_in[12];
    const float* W2 = (const float*)d_in[13];
    const float* as2 = (const float*)d_in[14];
    const float* ad2 = (const float*)d_in[15];
    const float* bb2 = (const float*)d_in[16];
    const float* ln_g = (const float*)d_in[17];
    const float* ln_b = (const float*)d_in[18];
    const float* mw1 = (const float*)d_in[19];
    const float* mb1 = (const float*)d_in[20];
    const float* mw2 = (const float*)d_in[21];
    const float* mb2 = (const float*)d_in[22];
    const float* mw3 = (const float*)d_in[23];
    const float* mb3 = (const float*)d_in[24];

    const int B = in_sizes[0];
    const int E = in_sizes[2] / 2;
    const int num_users = in_sizes[3] / D128;
    const int num_items = in_sizes[4] / D128;
    const int N = num_users + num_items;
    const int* esrc = eidx;
    const int* edst = eidx + E;

    size_t wsoff = 0;
    auto alloc = [&](size_t bytes) {
        void* p = (char*)d_ws + wsoff;
        wsoff += (bytes + 255) & ~(size_t)255;
        return p;
    };
    float* bufA = (float*)alloc((size_t)N * 128 * 4);
    float* bufB = (float*)alloc((size_t)N * 128 * 4);
    unsigned short* hb = (unsigned short*)alloc((size_t)N * 128 * 2);
    float* aS = (float*)alloc((size_t)N * 4 * 4);
    float* aD = (float*)alloc((size_t)N * 4 * 4);
    float* pbuf = (float*)alloc((size_t)E * 4 * 4);
    int* cnt = (int*)alloc((size_t)(N + 1) * 4);
    int* off = (int*)alloc((size_t)(N + 1) * 4);
    int* cur = (int*)alloc((size_t)(N + 1) * 4);
    int* csr_src = (int*)alloc((size_t)E * 4);
    int* csr_dst = (int*)alloc((size_t)E * 4);
    int* partials = (int*)alloc(64 * 4);
    int* pp = (int*)alloc(64 * 4);
    (void)ws_size;

    const int NB = (N + SCAN_CHUNK - 1) / SCAN_CHUNK;
    zero_int_kernel<<<(N + 255) / 256, 256, 0, stream>>>(cnt, N);
    count_kernel<<<(E + 255) / 256, 256, 0, stream>>>(edst, E, cnt);
    scan_local_kernel<<<NB, SB, 0, stream>>>(cnt, off, partials, N);
    scan_partials_kernel<<<1, 64, 0, stream>>>(partials, pp, NB, off, N);
    scan_add_kernel<<<(N + 255) / 256, 256, 0, stream>>>(off, cur, pp, N);
    fill_kernel<<<(E + 255) / 256, 256, 0, stream>>>(esrc, edst, E, cur, csr_src, csr_dst);

    const int gemm_grid = (N + 63) / 64;
    const int egrid = (E + 255) / 256;
    const int agrid = (N + 3) / 4;

    // ---- layer 0 (H=4, C=32, no residual; X = virtual concat of tables) ----
    gemm_att_kernel<4, 32, true><<<gemm_grid, 256, 0, stream>>>(utab, itab, num_users, W0, as0,
                                                                ad0, hb, aS, aD, N);
    pk4_kernel<<<egrid, 256, 0, stream>>>(csr_src, csr_dst, aS, aD, pbuf, E);
    agg_kernel<4, false><<<agrid, 256, 0, stream>>>(hb, pbuf, off, csr_src, nullptr, bb0, ln_g,
                                                    ln_b, bufB, N);
    // ---- layer 1 (H=4, residual) ----
    gemm_att_kernel<4, 32, false><<<gemm_grid, 256, 0, stream>>>(bufB, nullptr, 0, W1, as1, ad1,
                                                                 hb, aS, aD, N);
    pk4_kernel<<<egrid, 256, 0, stream>>>(csr_src, csr_dst, aS, aD, pbuf, E);
    agg_kernel<4, true><<<agrid, 256, 0, stream>>>(hb, pbuf, off, csr_src, bufB, bb1, ln_g,
                                                   ln_b, bufA, N);
    // ---- layer 2 (H=1, residual) ----
    gemm_att_kernel<1, 128, false><<<gemm_grid, 256, 0, stream>>>(bufA, nullptr, 0, W2, as2,
                                                                  ad2, hb, aS, aD, N);
    pk1_kernel<<<egrid, 256, 0, stream>>>(csr_src, csr_dst, aS, aD, pbuf, E);
    agg_kernel<1, true><<<agrid, 256, 0, stream>>>(hb, pbuf, off, csr_src, bufA, bb2, ln_g,
                                                   ln_b, bufB, N);

    // ---- prediction MLP ----
    mlp_kernel<<<(B + 31) / 32, 256, 0, stream>>>(bufB, uidx, vidx, num_users, mw1, mb1, mw2,
                                                  mb2, mw3, mb3, (float*)d_out, B);
}

// Round 7
// 325.797 us; speedup vs baseline: 2.3942x; 1.1152x over previous
//
#include <hip/hip_runtime.h>
#include <hip/hip_bf16.h>

#define D128 128
#define NEG_SLOPE 0.2f

typedef __attribute__((ext_vector_type(8))) short bf16x8;
typedef __attribute__((ext_vector_type(4))) float f32x4;

__device__ inline float bf2f(unsigned short u) {
    return __uint_as_float(((unsigned)u) << 16);
}
__device__ inline unsigned short f2bf(float f) {  // RTNE
    unsigned u = __float_as_uint(f);
    unsigned r = (u + 0x7fffu + ((u >> 16) & 1u)) >> 16;
    return (unsigned short)r;
}

// ---------------------------------------------------------------------------
// CSR build
// ---------------------------------------------------------------------------
__global__ void zero_int_kernel(int* __restrict__ p, int n) {
    int i = blockIdx.x * blockDim.x + threadIdx.x;
    if (i < n) p[i] = 0;
}

__global__ void count_kernel(const int* __restrict__ dst, int E, int* __restrict__ cnt) {
    int e = blockIdx.x * blockDim.x + threadIdx.x;
    if (e < E) atomicAdd(&cnt[dst[e]], 1);
}

#define SB 256
#define SCAN_CHUNK 2048  // SB * 8

__global__ __launch_bounds__(SB) void scan_local_kernel(const int* __restrict__ cnt,
                                                        int* __restrict__ off,
                                                        int* __restrict__ partials, int N) {
    __shared__ int lds[SB];
    const int b = blockIdx.x;
    const int t = threadIdx.x;
    const int base = b * SCAN_CHUNK + t * 8;
    int v[8];
    int s = 0;
#pragma unroll
    for (int j = 0; j < 8; ++j) {
        int i = base + j;
        v[j] = (i < N) ? cnt[i] : 0;
        s += v[j];
    }
    lds[t] = s;
    __syncthreads();
    for (int d = 1; d < SB; d <<= 1) {
        int y = (t >= d) ? lds[t - d] : 0;
        __syncthreads();
        lds[t] += y;
        __syncthreads();
    }
    int pref = lds[t] - s;
#pragma unroll
    for (int j = 0; j < 8; ++j) {
        int i = base + j;
        if (i < N) off[i] = pref;
        pref += v[j];
    }
    if (t == SB - 1) partials[b] = lds[t];
}

__global__ __launch_bounds__(64) void scan_partials_kernel(int* __restrict__ partials,
                                                           int* __restrict__ pp, int NB,
                                                           int* __restrict__ off, int N) {
    __shared__ int lds[64];
    int t = threadIdx.x;
    int v = (t < NB) ? partials[t] : 0;
    lds[t] = v;
    __syncthreads();
    for (int d = 1; d < 64; d <<= 1) {
        int y = (t >= d) ? lds[t - d] : 0;
        __syncthreads();
        lds[t] += y;
        __syncthreads();
    }
    pp[t] = lds[t] - v;
    if (t == 63) off[N] = lds[63];
}

__global__ void scan_add_kernel(int* __restrict__ off, int* __restrict__ cur,
                                const int* __restrict__ pp, int N) {
    int i = blockIdx.x * blockDim.x + threadIdx.x;
    if (i < N) {
        int o = off[i] + pp[i / SCAN_CHUNK];
        off[i] = o;
        cur[i] = o;
    }
}

__global__ void fill_kernel(const int* __restrict__ src, const int* __restrict__ dst, int E,
                            int* __restrict__ cur, int* __restrict__ csr_src,
                            int* __restrict__ csr_dst) {
    int e = blockIdx.x * blockDim.x + threadIdx.x;
    if (e < E) {
        int d = dst[e];
        int p = atomicAdd(&cur[d], 1);
        csr_src[p] = src[e];
        csr_dst[p] = d;
    }
}

// ---------------------------------------------------------------------------
// W repack into MFMA B-fragment order, split hi/lo bf16.
// Wb[(ct*4+kk)*64*8 + lane*8 + j] = W[kk*32 + (lane>>4)*8 + j][ct*16 + (lane&15)]
// hi at offset 0, lo at offset 16384.
// ---------------------------------------------------------------------------
__global__ __launch_bounds__(256) void wrepack_kernel(const float* __restrict__ W,
                                                      unsigned short* __restrict__ Wb) {
    int i = blockIdx.x * 256 + threadIdx.x;  // 0..16383
    if (i >= 16384) return;
    int j = i & 7;
    int l = (i >> 3) & 63;
    int kk = (i >> 9) & 3;
    int ct = i >> 11;
    int k = kk * 32 + ((l >> 4) & 3) * 8 + j;
    int c = ct * 16 + (l & 15);
    float w = W[k * 128 + c];
    unsigned short hi = f2bf(w);
    unsigned short lo = f2bf(w - bf2f(hi));
    Wb[i] = hi;
    Wb[16384 + i] = lo;
}

// ---------------------------------------------------------------------------
// MFMA GEMM (split-bf16 ~ fp32 accuracy) fused with attention scalars.
// Per wave: 16 rows x 128 cols.  96 x mfma_f32_16x16x32_bf16.  No LDS.
// h written bf16; a_s/a_d from exact fp32 acc via 16-lane butterfly.
// ---------------------------------------------------------------------------
template <int H, bool SPLIT>
__global__ __launch_bounds__(256) void gemm_mfma_kernel(const float* __restrict__ X0,
                                                        const float* __restrict__ X1, int split,
                                                        const unsigned short* __restrict__ Wb,
                                                        const float* __restrict__ att_s,
                                                        const float* __restrict__ att_d,
                                                        unsigned short* __restrict__ hb,
                                                        float* __restrict__ a_s,
                                                        float* __restrict__ a_d, int N) {
    const int t = threadIdx.x;
    const int lane = t & 63;
    const int wave = t >> 6;
    const int row0 = blockIdx.x * 64 + wave * 16;
    if (row0 >= N) return;

    const int lr = lane & 15;  // A-row / B-col / D-col within tile
    const int lk = lane >> 4;  // k sub-chunk

    int arow = row0 + lr;
    if (arow >= N) arow = N - 1;  // clamp; results for padded rows never stored
    const float* xrow;
    if (SPLIT)
        xrow = (arow < split) ? &X0[(size_t)arow * 128] : &X1[(size_t)(arow - split) * 128];
    else
        xrow = &X0[(size_t)arow * 128];

    // load + split A fragments
    bf16x8 ahi[4], alo[4];
#pragma unroll
    for (int kk = 0; kk < 4; ++kk) {
        const float* ap = &xrow[kk * 32 + lk * 8];
        float4 v0 = *(const float4*)ap;
        float4 v1 = *(const float4*)(ap + 4);
        float f[8] = {v0.x, v0.y, v0.z, v0.w, v1.x, v1.y, v1.z, v1.w};
#pragma unroll
        for (int j = 0; j < 8; ++j) {
            unsigned short hi = f2bf(f[j]);
            unsigned short lo = f2bf(f[j] - bf2f(hi));
            ((short*)&ahi[kk])[j] = (short)hi;
            ((short*)&alo[kk])[j] = (short)lo;
        }
    }

    f32x4 acc[8];
#pragma unroll
    for (int ct = 0; ct < 8; ++ct) acc[ct] = (f32x4){0.f, 0.f, 0.f, 0.f};

#pragma unroll
    for (int kk = 0; kk < 4; ++kk) {
#pragma unroll
        for (int ct = 0; ct < 8; ++ct) {
            const size_t fo = ((size_t)(ct * 4 + kk) * 64 + lane) * 8;
            bf16x8 bhi = *(const bf16x8*)&Wb[fo];
            bf16x8 blo = *(const bf16x8*)&Wb[16384 + fo];
            acc[ct] = __builtin_amdgcn_mfma_f32_16x16x32_bf16(ahi[kk], bhi, acc[ct], 0, 0, 0);
            acc[ct] = __builtin_amdgcn_mfma_f32_16x16x32_bf16(ahi[kk], blo, acc[ct], 0, 0, 0);
            acc[ct] = __builtin_amdgcn_mfma_f32_16x16x32_bf16(alo[kk], bhi, acc[ct], 0, 0, 0);
        }
    }

    // epilogue: store h (bf16) + attention dot products
    float ps[4][H], pd[4][H];
#pragma unroll
    for (int r = 0; r < 4; ++r)
#pragma unroll
        for (int h = 0; h < H; ++h) { ps[r][h] = 0.f; pd[r][h] = 0.f; }

#pragma unroll
    for (int ct = 0; ct < 8; ++ct) {
        float as_c = att_s[ct * 16 + lr];
        float ad_c = att_d[ct * 16 + lr];
        const int h = (ct * H) >> 3;
#pragma unroll
        for (int r = 0; r < 4; ++r) {
            float v = acc[ct][r];
            int row = row0 + lk * 4 + r;
            if (row < N) hb[(size_t)row * 128 + ct * 16 + lr] = f2bf(v);
            ps[r][h] += v * as_c;
            pd[r][h] += v * ad_c;
        }
    }

    // butterfly over the 16 col-lanes (lane bits 0..3)
#pragma unroll
    for (int m = 1; m < 16; m <<= 1) {
#pragma unroll
        for (int r = 0; r < 4; ++r)
#pragma unroll
            for (int h = 0; h < H; ++h) {
                ps[r][h] += __shfl_xor(ps[r][h], m);
                pd[r][h] += __shfl_xor(pd[r][h], m);
            }
    }
    if (lr == 0) {
#pragma unroll
        for (int r = 0; r < 4; ++r) {
            int row = row0 + lk * 4 + r;
            if (row < N) {
                if (H == 4) {
                    *(float4*)&a_s[(size_t)row * 4] =
                        make_float4(ps[r][0], ps[r][1], ps[r][2], ps[r][3]);
                    *(float4*)&a_d[(size_t)row * 4] =
                        make_float4(pd[r][0], pd[r][1], pd[r][2], pd[r][3]);
                } else {
                    a_s[row] = ps[r][0];
                    a_d[row] = pd[r][0];
                }
            }
        }
    }
}

// ---------------------------------------------------------------------------
// per-edge softmax numerator p = exp(leaky_relu(a_s[src]+a_d[dst]))
// ---------------------------------------------------------------------------
__global__ void pk4_kernel(const int* __restrict__ csr_src, const int* __restrict__ csr_dst,
                           const float* __restrict__ a_s, const float* __restrict__ a_d,
                           float* __restrict__ pbuf, int E) {
    int i = blockIdx.x * blockDim.x + threadIdx.x;
    if (i >= E) return;
    int s = csr_src[i], d = csr_dst[i];
    const float4 as4 = *(const float4*)&a_s[(size_t)s * 4];
    const float4 ad4 = *(const float4*)&a_d[(size_t)d * 4];
    float4 o;
    float lg;
    lg = as4.x + ad4.x; lg = lg >= 0.f ? lg : NEG_SLOPE * lg; o.x = expf(lg);
    lg = as4.y + ad4.y; lg = lg >= 0.f ? lg : NEG_SLOPE * lg; o.y = expf(lg);
    lg = as4.z + ad4.z; lg = lg >= 0.f ? lg : NEG_SLOPE * lg; o.z = expf(lg);
    lg = as4.w + ad4.w; lg = lg >= 0.f ? lg : NEG_SLOPE * lg; o.w = expf(lg);
    *(float4*)&pbuf[(size_t)i * 4] = o;
}

__global__ void pk1_kernel(const int* __restrict__ csr_src, const int* __restrict__ csr_dst,
                           const float* __restrict__ a_s, const float* __restrict__ a_d,
                           float* __restrict__ pbuf, int E) {
    int i = blockIdx.x * blockDim.x + threadIdx.x;
    if (i >= E) return;
    float lg = a_s[csr_src[i]] + a_d[csr_dst[i]];
    lg = lg >= 0.f ? lg : NEG_SLOPE * lg;
    pbuf[i] = expf(lg);
}

// ---------------------------------------------------------------------------
// aggregation + bias + ELU + residual + LayerNorm.  One wave per node.
// ---------------------------------------------------------------------------
template <int H, bool RES>
__global__ __launch_bounds__(256) void agg_kernel(const unsigned short* __restrict__ hb,
                                                  const float* __restrict__ pbuf,
                                                  const int* __restrict__ off,
                                                  const int* __restrict__ csr_src,
                                                  const float* __restrict__ xprev,
                                                  const float* __restrict__ bias,
                                                  const float* __restrict__ ln_g,
                                                  const float* __restrict__ ln_b,
                                                  float* __restrict__ xout, int N) {
    const int lane = threadIdx.x & 63;
    const int n = blockIdx.x * 4 + (threadIdx.x >> 6);
    if (n >= N) return;
    const int c2 = lane * 2;
    const int head = (c2 * H) >> 7;
    const int base = off[n];
    const int deg = off[n + 1] - base;

    float a0 = 0.f, a1 = 0.f, ps0 = 0.f;
    float b0 = 0.f, b1 = 0.f, ps1 = 0.f;
    int e = 0;
    for (; e + 1 < deg; e += 2) {
        int s0 = csr_src[base + e];
        int s1 = csr_src[base + e + 1];
        float p0 = pbuf[(size_t)(base + e) * H + head];
        float p1 = pbuf[(size_t)(base + e + 1) * H + head];
        unsigned hv0 = *(const unsigned*)&hb[((size_t)s0 << 7) + c2];
        unsigned hv1 = *(const unsigned*)&hb[((size_t)s1 << 7) + c2];
        ps0 += p0;
        ps1 += p1;
        a0 = fmaf(p0, bf2f((unsigned short)hv0), a0);
        a1 = fmaf(p0, bf2f((unsigned short)(hv0 >> 16)), a1);
        b0 = fmaf(p1, bf2f((unsigned short)hv1), b0);
        b1 = fmaf(p1, bf2f((unsigned short)(hv1 >> 16)), b1);
    }
    if (e < deg) {
        int s0 = csr_src[base + e];
        float p0 = pbuf[(size_t)(base + e) * H + head];
        unsigned hv0 = *(const unsigned*)&hb[((size_t)s0 << 7) + c2];
        ps0 += p0;
        a0 = fmaf(p0, bf2f((unsigned short)hv0), a0);
        a1 = fmaf(p0, bf2f((unsigned short)(hv0 >> 16)), a1);
    }
    a0 += b0;
    a1 += b1;
    float psum = ps0 + ps1;

    float inv = 1.0f / (psum + 1e-16f);
    float acc0 = a0 * inv + bias[c2];
    float acc1 = a1 * inv + bias[c2 + 1];
    acc0 = acc0 > 0.f ? acc0 : (expf(acc0) - 1.0f);
    acc1 = acc1 > 0.f ? acc1 : (expf(acc1) - 1.0f);
    if (RES) {
        float2 xp = *(const float2*)&xprev[((size_t)n << 7) + c2];
        acc0 += xp.x;
        acc1 += xp.y;
    }

    float s1v = acc0 + acc1;
    float s2v = acc0 * acc0 + acc1 * acc1;
#pragma unroll
    for (int m = 1; m < 64; m <<= 1) {
        s1v += __shfl_xor(s1v, m);
        s2v += __shfl_xor(s2v, m);
    }
    float mu = s1v * (1.0f / 128.0f);
    float var = s2v * (1.0f / 128.0f) - mu * mu;
    float rstd = rsqrtf(var + 1e-5f);
    float2 o;
    o.x = (acc0 - mu) * rstd * ln_g[c2] + ln_b[c2];
    o.y = (acc1 - mu) * rstd * ln_g[c2 + 1] + ln_b[c2 + 1];
    *(float2*)&xout[((size_t)n << 7) + c2] = o;
}

// ---------------------------------------------------------------------------
// fused prediction MLP: 32 rows per 256-thread block, 8-deep weight prefetch.
// ---------------------------------------------------------------------------
__global__ __launch_bounds__(256) void mlp_kernel(const float* __restrict__ x,
                                                  const int* __restrict__ uidx,
                                                  const int* __restrict__ vidx, int num_users,
                                                  const float* __restrict__ mw1,
                                                  const float* __restrict__ mb1,
                                                  const float* __restrict__ mw2,
                                                  const float* __restrict__ mb2,
                                                  const float* __restrict__ mw3,
                                                  const float* __restrict__ mb3,
                                                  float* __restrict__ out, int B) {
    __shared__ float xs[32][128];
    __shared__ float h1s[32][128];
    __shared__ float h2s[32][66];
    const int t = threadIdx.x;
    const int b0 = blockIdx.x * 32;
    const int c0 = (t & 31) * 4;
    const int r0 = (t >> 5) * 4;

    float acc[4][4];
    const float4 bias1 = *(const float4*)&mb1[c0];
#pragma unroll
    for (int r = 0; r < 4; ++r) {
        acc[r][0] = bias1.x; acc[r][1] = bias1.y;
        acc[r][2] = bias1.z; acc[r][3] = bias1.w;
    }

    for (int i = t; i < 32 * 32; i += 256) {
        int r = i >> 5, c = (i & 31) * 4;
        int b = b0 + r;
        float4 v = make_float4(0.f, 0.f, 0.f, 0.f);
        if (b < B) v = *(const float4*)&x[(size_t)uidx[b] * 128 + c];
        *(float4*)&xs[r][c] = v;
    }
    __syncthreads();
    for (int k = 0; k < 128; k += 8) {
        float4 w[8];
#pragma unroll
        for (int j = 0; j < 8; ++j) w[j] = *(const float4*)&mw1[(k + j) * 128 + c0];
#pragma unroll
        for (int j = 0; j < 8; ++j)
#pragma unroll
            for (int r = 0; r < 4; ++r) {
                float xv = xs[r0 + r][k + j];
                acc[r][0] += xv * w[j].x; acc[r][1] += xv * w[j].y;
                acc[r][2] += xv * w[j].z; acc[r][3] += xv * w[j].w;
            }
    }
    __syncthreads();

    for (int i = t; i < 32 * 32; i += 256) {
        int r = i >> 5, c = (i & 31) * 4;
        int b = b0 + r;
        float4 v = make_float4(0.f, 0.f, 0.f, 0.f);
        if (b < B) v = *(const float4*)&x[(size_t)(vidx[b] + num_users) * 128 + c];
        *(float4*)&xs[r][c] = v;
    }
    __syncthreads();
    for (int k = 0; k < 128; k += 8) {
        float4 w[8];
#pragma unroll
        for (int j = 0; j < 8; ++j) w[j] = *(const float4*)&mw1[(128 + k + j) * 128 + c0];
#pragma unroll
        for (int j = 0; j < 8; ++j)
#pragma unroll
            for (int r = 0; r < 4; ++r) {
                float xv = xs[r0 + r][k + j];
                acc[r][0] += xv * w[j].x; acc[r][1] += xv * w[j].y;
                acc[r][2] += xv * w[j].z; acc[r][3] += xv * w[j].w;
            }
    }

#pragma unroll
    for (int r = 0; r < 4; ++r) {
        float4 h;
        h.x = fmaxf(acc[r][0], 0.f); h.y = fmaxf(acc[r][1], 0.f);
        h.z = fmaxf(acc[r][2], 0.f); h.w = fmaxf(acc[r][3], 0.f);
        *(float4*)&h1s[r0 + r][c0] = h;
    }
    __syncthreads();

    const int c2 = (t & 31) * 2;
    float acc2[4][2];
    const float b2x = mb2[c2], b2y = mb2[c2 + 1];
#pragma unroll
    for (int r = 0; r < 4; ++r) { acc2[r][0] = b2x; acc2[r][1] = b2y; }

    for (int k = 0; k < 128; k += 8) {
        float2 w[8];
#pragma unroll
        for (int j = 0; j < 8; ++j) w[j] = *(const float2*)&mw2[(k + j) * 64 + c2];
#pragma unroll
        for (int r = 0; r < 4; ++r) {
            float4 h0 = *(const float4*)&h1s[r0 + r][k];
            float4 h1 = *(const float4*)&h1s[r0 + r][k + 4];
            acc2[r][0] += h0.x * w[0].x + h0.y * w[1].x + h0.z * w[2].x + h0.w * w[3].x +
                          h1.x * w[4].x + h1.y * w[5].x + h1.z * w[6].x + h1.w * w[7].x;
            acc2[r][1] += h0.x * w[0].y + h0.y * w[1].y + h0.z * w[2].y + h0.w * w[3].y +
                          h1.x * w[4].y + h1.y * w[5].y + h1.z * w[6].y + h1.w * w[7].y;
        }
    }

#pragma unroll
    for (int r = 0; r < 4; ++r) {
        float2 h;
        h.x = fmaxf(acc2[r][0], 0.f);
        h.y = fmaxf(acc2[r][1], 0.f);
        *(float2*)&h2s[r0 + r][c2] = h;
    }
    __syncthreads();

    {
        const int row = t >> 3, q = t & 7;
        float s = 0.f;
        const float* hrow = &h2s[row][q * 8];
        const float* wrow = &mw3[q * 8];
#pragma unroll
        for (int kk = 0; kk < 8; ++kk) s += hrow[kk] * wrow[kk];
        s += __shfl_xor(s, 1);
        s += __shfl_xor(s, 2);
        s += __shfl_xor(s, 4);
        int b = b0 + row;
        if (q == 0 && b < B) out[b] = 1.0f / (1.0f + expf(-(s + mb3[0])));
    }
}

// ---------------------------------------------------------------------------
// launcher
// ---------------------------------------------------------------------------
extern "C" void kernel_launch(void* const* d_in, const int* in_sizes, int n_in,
                              void* d_out, int out_size, void* d_ws, size_t ws_size,
                              hipStream_t stream) {
    const int* uidx = (const int*)d_in[0];
    const int* vidx = (const int*)d_in[1];
    const int* eidx = (const int*)d_in[2];
    const float* utab = (const float*)d_in[3];
    const float* itab = (const float*)d_in[4];
    const float* W0 = (const float*)d_in[5];
    const float* as0 = (const float*)d_in[6];
    const float* ad0 = (const float*)d_in[7];
    const float* bb0 = (const float*)d_in[8];
    const float* W1 = (const float*)d_in[9];
    const float* as1 = (const float*)d_in[10];
    const float* ad1 = (const float*)d_in[11];
    const float* bb1 = (const float*)d_in[12];
    const float* W2 = (const float*)d_in[13];
    const float* as2 = (const float*)d_in[14];
    const float* ad2 = (const float*)d_in[15];
    const float* bb2 = (const float*)d_in[16];
    const float* ln_g = (const float*)d_in[17];
    const float* ln_b = (const float*)d_in[18];
    const float* mw1 = (const float*)d_in[19];
    const float* mb1 = (const float*)d_in[20];
    const float* mw2 = (const float*)d_in[21];
    const float* mb2 = (const float*)d_in[22];
    const float* mw3 = (const float*)d_in[23];
    const float* mb3 = (const float*)d_in[24];

    const int B = in_sizes[0];
    const int E = in_sizes[2] / 2;
    const int num_users = in_sizes[3] / D128;
    const int num_items = in_sizes[4] / D128;
    const int N = num_users + num_items;
    const int* esrc = eidx;
    const int* edst = eidx + E;

    size_t wsoff = 0;
    auto alloc = [&](size_t bytes) {
        void* p = (char*)d_ws + wsoff;
        wsoff += (bytes + 255) & ~(size_t)255;
        return p;
    };
    float* bufA = (float*)alloc((size_t)N * 128 * 4);
    float* bufB = (float*)alloc((size_t)N * 128 * 4);
    unsigned short* hb = (unsigned short*)alloc((size_t)N * 128 * 2);
    float* aS = (float*)alloc((size_t)N * 4 * 4);
    float* aD = (float*)alloc((size_t)N * 4 * 4);
    float* pbuf = (float*)alloc((size_t)E * 4 * 4);
    int* cnt = (int*)alloc((size_t)(N + 1) * 4);
    int* off = (int*)alloc((size_t)(N + 1) * 4);
    int* cur = (int*)alloc((size_t)(N + 1) * 4);
    int* csr_src = (int*)alloc((size_t)E * 4);
    int* csr_dst = (int*)alloc((size_t)E * 4);
    int* partials = (int*)alloc(64 * 4);
    int* pp = (int*)alloc(64 * 4);
    unsigned short* wb0 = (unsigned short*)alloc(2 * 16384 * 2);
    unsigned short* wb1 = (unsigned short*)alloc(2 * 16384 * 2);
    unsigned short* wb2 = (unsigned short*)alloc(2 * 16384 * 2);
    (void)ws_size;

    // W repacks (independent of x) + CSR build
    wrepack_kernel<<<64, 256, 0, stream>>>(W0, wb0);
    wrepack_kernel<<<64, 256, 0, stream>>>(W1, wb1);
    wrepack_kernel<<<64, 256, 0, stream>>>(W2, wb2);

    const int NB = (N + SCAN_CHUNK - 1) / SCAN_CHUNK;
    zero_int_kernel<<<(N + 255) / 256, 256, 0, stream>>>(cnt, N);
    count_kernel<<<(E + 255) / 256, 256, 0, stream>>>(edst, E, cnt);
    scan_local_kernel<<<NB, SB, 0, stream>>>(cnt, off, partials, N);
    scan_partials_kernel<<<1, 64, 0, stream>>>(partials, pp, NB, off, N);
    scan_add_kernel<<<(N + 255) / 256, 256, 0, stream>>>(off, cur, pp, N);
    fill_kernel<<<(E + 255) / 256, 256, 0, stream>>>(esrc, edst, E, cur, csr_src, csr_dst);

    const int gemm_grid = (N + 63) / 64;
    const int egrid = (E + 255) / 256;
    const int agrid = (N + 3) / 4;

    // ---- layer 0 (H=4, no residual; X = virtual concat of tables) ----
    gemm_mfma_kernel<4, true><<<gemm_grid, 256, 0, stream>>>(utab, itab, num_users, wb0, as0,
                                                             ad0, hb, aS, aD, N);
    pk4_kernel<<<egrid, 256, 0, stream>>>(csr_src, csr_dst, aS, aD, pbuf, E);
    agg_kernel<4, false><<<agrid, 256, 0, stream>>>(hb, pbuf, off, csr_src, nullptr, bb0, ln_g,
                                                    ln_b, bufB, N);
    // ---- layer 1 (H=4, residual) ----
    gemm_mfma_kernel<4, false><<<gemm_grid, 256, 0, stream>>>(bufB, nullptr, 0, wb1, as1, ad1,
                                                              hb, aS, aD, N);
    pk4_kernel<<<egrid, 256, 0, stream>>>(csr_src, csr_dst, aS, aD, pbuf, E);
    agg_kernel<4, true><<<agrid, 256, 0, stream>>>(hb, pbuf, off, csr_src, bufB, bb1, ln_g,
                                                   ln_b, bufA, N);
    // ---- layer 2 (H=1, residual) ----
    gemm_mfma_kernel<1, false><<<gemm_grid, 256, 0, stream>>>(bufA, nullptr, 0, wb2, as2, ad2,
                                                              hb, aS, aD, N);
    pk1_kernel<<<egrid, 256, 0, stream>>>(csr_src, csr_dst, aS, aD, pbuf, E);
    agg_kernel<1, true><<<agrid, 256, 0, stream>>>(hb, pbuf, off, csr_src, bufA, bb2, ln_g,
                                                   ln_b, bufB, N);

    // ---- prediction MLP ----
    mlp_kernel<<<(B + 31) / 32, 256, 0, stream>>>(bufB, uidx, vidx, num_users, mw1, mb1, mw2,
                                                  mb2, mw3, mb3, (float*)d_out, B);
}

// Round 8
// 303.897 us; speedup vs baseline: 2.5668x; 1.0721x over previous
//
#include <hip/hip_runtime.h>
#include <hip/hip_bf16.h>

#define D128 128
#define NEG_SLOPE 0.2f

typedef __attribute__((ext_vector_type(8))) short bf16x8;
typedef __attribute__((ext_vector_type(4))) float f32x4;

__device__ inline float bf2f(unsigned short u) {
    return __uint_as_float(((unsigned)u) << 16);
}
__device__ inline unsigned short f2bf(float f) {  // RTNE
    unsigned u = __float_as_uint(f);
    unsigned r = (u + 0x7fffu + ((u >> 16) & 1u)) >> 16;
    return (unsigned short)r;
}

// ---------------------------------------------------------------------------
// CSR build
// ---------------------------------------------------------------------------
__global__ void zero_int_kernel(int* __restrict__ p, int n) {
    int i = blockIdx.x * blockDim.x + threadIdx.x;
    if (i < n) p[i] = 0;
}

__global__ void count_kernel(const int* __restrict__ dst, int E, int* __restrict__ cnt) {
    int e = blockIdx.x * blockDim.x + threadIdx.x;
    if (e < E) atomicAdd(&cnt[dst[e]], 1);
}

#define SB 256
#define SCAN_CHUNK 2048  // SB * 8

__global__ __launch_bounds__(SB) void scan_local_kernel(const int* __restrict__ cnt,
                                                        int* __restrict__ off,
                                                        int* __restrict__ partials, int N) {
    __shared__ int lds[SB];
    const int b = blockIdx.x;
    const int t = threadIdx.x;
    const int base = b * SCAN_CHUNK + t * 8;
    int v[8];
    int s = 0;
#pragma unroll
    for (int j = 0; j < 8; ++j) {
        int i = base + j;
        v[j] = (i < N) ? cnt[i] : 0;
        s += v[j];
    }
    lds[t] = s;
    __syncthreads();
    for (int d = 1; d < SB; d <<= 1) {
        int y = (t >= d) ? lds[t - d] : 0;
        __syncthreads();
        lds[t] += y;
        __syncthreads();
    }
    int pref = lds[t] - s;
#pragma unroll
    for (int j = 0; j < 8; ++j) {
        int i = base + j;
        if (i < N) off[i] = pref;
        pref += v[j];
    }
    if (t == SB - 1) partials[b] = lds[t];
}

__global__ __launch_bounds__(64) void scan_partials_kernel(int* __restrict__ partials,
                                                           int* __restrict__ pp, int NB,
                                                           int* __restrict__ off, int N) {
    __shared__ int lds[64];
    int t = threadIdx.x;
    int v = (t < NB) ? partials[t] : 0;
    lds[t] = v;
    __syncthreads();
    for (int d = 1; d < 64; d <<= 1) {
        int y = (t >= d) ? lds[t - d] : 0;
        __syncthreads();
        lds[t] += y;
        __syncthreads();
    }
    pp[t] = lds[t] - v;
    if (t == 63) off[N] = lds[63];
}

__global__ void scan_add_kernel(int* __restrict__ off, int* __restrict__ cur,
                                const int* __restrict__ pp, int N) {
    int i = blockIdx.x * blockDim.x + threadIdx.x;
    if (i < N) {
        int o = off[i] + pp[i / SCAN_CHUNK];
        off[i] = o;
        cur[i] = o;
    }
}

__global__ void fill_kernel(const int* __restrict__ src, const int* __restrict__ dst, int E,
                            int* __restrict__ cur, int* __restrict__ csr_src,
                            int* __restrict__ csr_dst) {
    int e = blockIdx.x * blockDim.x + threadIdx.x;
    if (e < E) {
        int d = dst[e];
        int p = atomicAdd(&cur[d], 1);
        csr_src[p] = src[e];
        csr_dst[p] = d;
    }
}

// ---------------------------------------------------------------------------
// W repack into MFMA B-fragment order, split hi/lo bf16.
// ---------------------------------------------------------------------------
__global__ __launch_bounds__(256) void wrepack_kernel(const float* __restrict__ W,
                                                      unsigned short* __restrict__ Wb) {
    int i = blockIdx.x * 256 + threadIdx.x;  // 0..16383
    if (i >= 16384) return;
    int j = i & 7;
    int l = (i >> 3) & 63;
    int kk = (i >> 9) & 3;
    int ct = i >> 11;
    int k = kk * 32 + ((l >> 4) & 3) * 8 + j;
    int c = ct * 16 + (l & 15);
    float w = W[k * 128 + c];
    unsigned short hi = f2bf(w);
    unsigned short lo = f2bf(w - bf2f(hi));
    Wb[i] = hi;
    Wb[16384 + i] = lo;
}

// ---------------------------------------------------------------------------
// MFMA GEMM (split-bf16 ~ fp32 accuracy) fused with attention scalars.
// ---------------------------------------------------------------------------
template <int H, bool SPLIT>
__global__ __launch_bounds__(256) void gemm_mfma_kernel(const float* __restrict__ X0,
                                                        const float* __restrict__ X1, int split,
                                                        const unsigned short* __restrict__ Wb,
                                                        const float* __restrict__ att_s,
                                                        const float* __restrict__ att_d,
                                                        unsigned short* __restrict__ hb,
                                                        float* __restrict__ a_s,
                                                        float* __restrict__ a_d, int N) {
    const int t = threadIdx.x;
    const int lane = t & 63;
    const int wave = t >> 6;
    const int row0 = blockIdx.x * 64 + wave * 16;
    if (row0 >= N) return;

    const int lr = lane & 15;
    const int lk = lane >> 4;

    int arow = row0 + lr;
    if (arow >= N) arow = N - 1;
    const float* xrow;
    if (SPLIT)
        xrow = (arow < split) ? &X0[(size_t)arow * 128] : &X1[(size_t)(arow - split) * 128];
    else
        xrow = &X0[(size_t)arow * 128];

    bf16x8 ahi[4], alo[4];
#pragma unroll
    for (int kk = 0; kk < 4; ++kk) {
        const float* ap = &xrow[kk * 32 + lk * 8];
        float4 v0 = *(const float4*)ap;
        float4 v1 = *(const float4*)(ap + 4);
        float f[8] = {v0.x, v0.y, v0.z, v0.w, v1.x, v1.y, v1.z, v1.w};
#pragma unroll
        for (int j = 0; j < 8; ++j) {
            unsigned short hi = f2bf(f[j]);
            unsigned short lo = f2bf(f[j] - bf2f(hi));
            ((short*)&ahi[kk])[j] = (short)hi;
            ((short*)&alo[kk])[j] = (short)lo;
        }
    }

    f32x4 acc[8];
#pragma unroll
    for (int ct = 0; ct < 8; ++ct) acc[ct] = (f32x4){0.f, 0.f, 0.f, 0.f};

#pragma unroll
    for (int kk = 0; kk < 4; ++kk) {
#pragma unroll
        for (int ct = 0; ct < 8; ++ct) {
            const size_t fo = ((size_t)(ct * 4 + kk) * 64 + lane) * 8;
            bf16x8 bhi = *(const bf16x8*)&Wb[fo];
            bf16x8 blo = *(const bf16x8*)&Wb[16384 + fo];
            acc[ct] = __builtin_amdgcn_mfma_f32_16x16x32_bf16(ahi[kk], bhi, acc[ct], 0, 0, 0);
            acc[ct] = __builtin_amdgcn_mfma_f32_16x16x32_bf16(ahi[kk], blo, acc[ct], 0, 0, 0);
            acc[ct] = __builtin_amdgcn_mfma_f32_16x16x32_bf16(alo[kk], bhi, acc[ct], 0, 0, 0);
        }
    }

    float ps[4][H], pd[4][H];
#pragma unroll
    for (int r = 0; r < 4; ++r)
#pragma unroll
        for (int h = 0; h < H; ++h) { ps[r][h] = 0.f; pd[r][h] = 0.f; }

#pragma unroll
    for (int ct = 0; ct < 8; ++ct) {
        float as_c = att_s[ct * 16 + lr];
        float ad_c = att_d[ct * 16 + lr];
        const int h = (ct * H) >> 3;
#pragma unroll
        for (int r = 0; r < 4; ++r) {
            float v = acc[ct][r];
            int row = row0 + lk * 4 + r;
            if (row < N) hb[(size_t)row * 128 + ct * 16 + lr] = f2bf(v);
            ps[r][h] += v * as_c;
            pd[r][h] += v * ad_c;
        }
    }

#pragma unroll
    for (int m = 1; m < 16; m <<= 1) {
#pragma unroll
        for (int r = 0; r < 4; ++r)
#pragma unroll
            for (int h = 0; h < H; ++h) {
                ps[r][h] += __shfl_xor(ps[r][h], m);
                pd[r][h] += __shfl_xor(pd[r][h], m);
            }
    }
    if (lr == 0) {
#pragma unroll
        for (int r = 0; r < 4; ++r) {
            int row = row0 + lk * 4 + r;
            if (row < N) {
                if (H == 4) {
                    *(float4*)&a_s[(size_t)row * 4] =
                        make_float4(ps[r][0], ps[r][1], ps[r][2], ps[r][3]);
                    *(float4*)&a_d[(size_t)row * 4] =
                        make_float4(pd[r][0], pd[r][1], pd[r][2], pd[r][3]);
                } else {
                    a_s[row] = ps[r][0];
                    a_d[row] = pd[r][0];
                }
            }
        }
    }
}

// ---------------------------------------------------------------------------
// per-edge softmax numerator p = exp(leaky_relu(a_s[src]+a_d[dst]))
// ---------------------------------------------------------------------------
__global__ void pk4_kernel(const int* __restrict__ csr_src, const int* __restrict__ csr_dst,
                           const float* __restrict__ a_s, const float* __restrict__ a_d,
                           float* __restrict__ pbuf, int E) {
    int i = blockIdx.x * blockDim.x + threadIdx.x;
    if (i >= E) return;
    int s = csr_src[i], d = csr_dst[i];
    const float4 as4 = *(const float4*)&a_s[(size_t)s * 4];
    const float4 ad4 = *(const float4*)&a_d[(size_t)d * 4];
    float4 o;
    float lg;
    lg = as4.x + ad4.x; lg = lg >= 0.f ? lg : NEG_SLOPE * lg; o.x = expf(lg);
    lg = as4.y + ad4.y; lg = lg >= 0.f ? lg : NEG_SLOPE * lg; o.y = expf(lg);
    lg = as4.z + ad4.z; lg = lg >= 0.f ? lg : NEG_SLOPE * lg; o.z = expf(lg);
    lg = as4.w + ad4.w; lg = lg >= 0.f ? lg : NEG_SLOPE * lg; o.w = expf(lg);
    *(float4*)&pbuf[(size_t)i * 4] = o;
}

__global__ void pk1_kernel(const int* __restrict__ csr_src, const int* __restrict__ csr_dst,
                           const float* __restrict__ a_s, const float* __restrict__ a_d,
                           float* __restrict__ pbuf, int E) {
    int i = blockIdx.x * blockDim.x + threadIdx.x;
    if (i >= E) return;
    float lg = a_s[csr_src[i]] + a_d[csr_dst[i]];
    lg = lg >= 0.f ? lg : NEG_SLOPE * lg;
    pbuf[i] = expf(lg);
}

// ---------------------------------------------------------------------------
// aggregation + bias + ELU + residual + LayerNorm.  One wave per node.
// Lane-parallel csr prefetch (+shfl broadcast) removes the 2-deep load chain;
// 4-way unroll keeps 4 independent gathers in flight.
// ---------------------------------------------------------------------------
template <int H, bool RES>
__global__ __launch_bounds__(256) void agg_kernel(const unsigned short* __restrict__ hb,
                                                  const float* __restrict__ pbuf,
                                                  const int* __restrict__ off,
                                                  const int* __restrict__ csr_src,
                                                  const float* __restrict__ xprev,
                                                  const float* __restrict__ bias,
                                                  const float* __restrict__ ln_g,
                                                  const float* __restrict__ ln_b,
                                                  float* __restrict__ xout, int N) {
    const int lane = threadIdx.x & 63;
    const int n = blockIdx.x * 4 + (threadIdx.x >> 6);
    if (n >= N) return;
    const int c2 = lane * 2;
    const int head = (c2 * H) >> 7;
    const int base = off[n];
    const int deg = off[n + 1] - base;

    float a0 = 0.f, a1 = 0.f;
    float b0 = 0.f, b1 = 0.f;
    float c0 = 0.f, c1 = 0.f;
    float d0 = 0.f, d1 = 0.f;
    float psum = 0.f;

    for (int e0 = 0; e0 < deg; e0 += 64) {
        const int ce = min(64, deg - e0);
        int myidx = 0;
        if (lane < ce) myidx = csr_src[base + e0 + lane];
        const float* pb = &pbuf[(size_t)(base + e0) * H + head];
        int e = 0;
        for (; e + 3 < ce; e += 4) {
            int s0 = __shfl(myidx, e);
            int s1 = __shfl(myidx, e + 1);
            int s2 = __shfl(myidx, e + 2);
            int s3 = __shfl(myidx, e + 3);
            float p0 = pb[(size_t)(e + 0) * H];
            float p1 = pb[(size_t)(e + 1) * H];
            float p2 = pb[(size_t)(e + 2) * H];
            float p3 = pb[(size_t)(e + 3) * H];
            unsigned hv0 = *(const unsigned*)&hb[((size_t)s0 << 7) + c2];
            unsigned hv1 = *(const unsigned*)&hb[((size_t)s1 << 7) + c2];
            unsigned hv2 = *(const unsigned*)&hb[((size_t)s2 << 7) + c2];
            unsigned hv3 = *(const unsigned*)&hb[((size_t)s3 << 7) + c2];
            psum += (p0 + p1) + (p2 + p3);
            a0 = fmaf(p0, bf2f((unsigned short)hv0), a0);
            a1 = fmaf(p0, bf2f((unsigned short)(hv0 >> 16)), a1);
            b0 = fmaf(p1, bf2f((unsigned short)hv1), b0);
            b1 = fmaf(p1, bf2f((unsigned short)(hv1 >> 16)), b1);
            c0 = fmaf(p2, bf2f((unsigned short)hv2), c0);
            c1 = fmaf(p2, bf2f((unsigned short)(hv2 >> 16)), c1);
            d0 = fmaf(p3, bf2f((unsigned short)hv3), d0);
            d1 = fmaf(p3, bf2f((unsigned short)(hv3 >> 16)), d1);
        }
        for (; e < ce; ++e) {
            int s0 = __shfl(myidx, e);
            float p0 = pb[(size_t)e * H];
            unsigned hv0 = *(const unsigned*)&hb[((size_t)s0 << 7) + c2];
            psum += p0;
            a0 = fmaf(p0, bf2f((unsigned short)hv0), a0);
            a1 = fmaf(p0, bf2f((unsigned short)(hv0 >> 16)), a1);
        }
    }
    a0 = (a0 + b0) + (c0 + d0);
    a1 = (a1 + b1) + (c1 + d1);

    float inv = 1.0f / (psum + 1e-16f);
    float acc0 = a0 * inv + bias[c2];
    float acc1 = a1 * inv + bias[c2 + 1];
    acc0 = acc0 > 0.f ? acc0 : (expf(acc0) - 1.0f);
    acc1 = acc1 > 0.f ? acc1 : (expf(acc1) - 1.0f);
    if (RES) {
        float2 xp = *(const float2*)&xprev[((size_t)n << 7) + c2];
        acc0 += xp.x;
        acc1 += xp.y;
    }

    float s1v = acc0 + acc1;
    float s2v = acc0 * acc0 + acc1 * acc1;
#pragma unroll
    for (int m = 1; m < 64; m <<= 1) {
        s1v += __shfl_xor(s1v, m);
        s2v += __shfl_xor(s2v, m);
    }
    float mu = s1v * (1.0f / 128.0f);
    float var = s2v * (1.0f / 128.0f) - mu * mu;
    float rstd = rsqrtf(var + 1e-5f);
    float2 o;
    o.x = (acc0 - mu) * rstd * ln_g[c2] + ln_b[c2];
    o.y = (acc1 - mu) * rstd * ln_g[c2 + 1] + ln_b[c2 + 1];
    *(float2*)&xout[((size_t)n << 7) + c2] = o;
}

// ---------------------------------------------------------------------------
// fused prediction MLP: 32 rows per 256-thread block, 8-deep weight prefetch.
// ---------------------------------------------------------------------------
__global__ __launch_bounds__(256) void mlp_kernel(const float* __restrict__ x,
                                                  const int* __restrict__ uidx,
                                                  const int* __restrict__ vidx, int num_users,
                                                  const float* __restrict__ mw1,
                                                  const float* __restrict__ mb1,
                                                  const float* __restrict__ mw2,
                                                  const float* __restrict__ mb2,
                                                  const float* __restrict__ mw3,
                                                  const float* __restrict__ mb3,
                                                  float* __restrict__ out, int B) {
    __shared__ float xs[32][128];
    __shared__ float h1s[32][128];
    __shared__ float h2s[32][66];
    const int t = threadIdx.x;
    const int b0 = blockIdx.x * 32;
    const int c0 = (t & 31) * 4;
    const int r0 = (t >> 5) * 4;

    float acc[4][4];
    const float4 bias1 = *(const float4*)&mb1[c0];
#pragma unroll
    for (int r = 0; r < 4; ++r) {
        acc[r][0] = bias1.x; acc[r][1] = bias1.y;
        acc[r][2] = bias1.z; acc[r][3] = bias1.w;
    }

    for (int i = t; i < 32 * 32; i += 256) {
        int r = i >> 5, c = (i & 31) * 4;
        int b = b0 + r;
        float4 v = make_float4(0.f, 0.f, 0.f, 0.f);
        if (b < B) v = *(const float4*)&x[(size_t)uidx[b] * 128 + c];
        *(float4*)&xs[r][c] = v;
    }
    __syncthreads();
    for (int k = 0; k < 128; k += 8) {
        float4 w[8];
#pragma unroll
        for (int j = 0; j < 8; ++j) w[j] = *(const float4*)&mw1[(k + j) * 128 + c0];
#pragma unroll
        for (int j = 0; j < 8; ++j)
#pragma unroll
            for (int r = 0; r < 4; ++r) {
                float xv = xs[r0 + r][k + j];
                acc[r][0] += xv * w[j].x; acc[r][1] += xv * w[j].y;
                acc[r][2] += xv * w[j].z; acc[r][3] += xv * w[j].w;
            }
    }
    __syncthreads();

    for (int i = t; i < 32 * 32; i += 256) {
        int r = i >> 5, c = (i & 31) * 4;
        int b = b0 + r;
        float4 v = make_float4(0.f, 0.f, 0.f, 0.f);
        if (b < B) v = *(const float4*)&x[(size_t)(vidx[b] + num_users) * 128 + c];
        *(float4*)&xs[r][c] = v;
    }
    __syncthreads();
    for (int k = 0; k < 128; k += 8) {
        float4 w[8];
#pragma unroll
        for (int j = 0; j < 8; ++j) w[j] = *(const float4*)&mw1[(128 + k + j) * 128 + c0];
#pragma unroll
        for (int j = 0; j < 8; ++j)
#pragma unroll
            for (int r = 0; r < 4; ++r) {
                float xv = xs[r0 + r][k + j];
                acc[r][0] += xv * w[j].x; acc[r][1] += xv * w[j].y;
                acc[r][2] += xv * w[j].z; acc[r][3] += xv * w[j].w;
            }
    }

#pragma unroll
    for (int r = 0; r < 4; ++r) {
        float4 h;
        h.x = fmaxf(acc[r][0], 0.f); h.y = fmaxf(acc[r][1], 0.f);
        h.z = fmaxf(acc[r][2], 0.f); h.w = fmaxf(acc[r][3], 0.f);
        *(float4*)&h1s[r0 + r][c0] = h;
    }
    __syncthreads();

    const int c2 = (t & 31) * 2;
    float acc2[4][2];
    const float b2x = mb2[c2], b2y = mb2[c2 + 1];
#pragma unroll
    for (int r = 0; r < 4; ++r) { acc2[r][0] = b2x; acc2[r][1] = b2y; }

    for (int k = 0; k < 128; k += 8) {
        float2 w[8];
#pragma unroll
        for (int j = 0; j < 8; ++j) w[j] = *(const float2*)&mw2[(k + j) * 64 + c2];
#pragma unroll
        for (int r = 0; r < 4; ++r) {
            float4 h0 = *(const float4*)&h1s[r0 + r][k];
            float4 h1 = *(const float4*)&h1s[r0 + r][k + 4];
            acc2[r][0] += h0.x * w[0].x + h0.y * w[1].x + h0.z * w[2].x + h0.w * w[3].x +
                          h1.x * w[4].x + h1.y * w[5].x + h1.z * w[6].x + h1.w * w[7].x;
            acc2[r][1] += h0.x * w[0].y + h0.y * w[1].y + h0.z * w[2].y + h0.w * w[3].y +
                          h1.x * w[4].y + h1.y * w[5].y + h1.z * w[6].y + h1.w * w[7].y;
        }
    }

#pragma unroll
    for (int r = 0; r < 4; ++r) {
        float2 h;
        h.x = fmaxf(acc2[r][0], 0.f);
        h.y = fmaxf(acc2[r][1], 0.f);
        *(float2*)&h2s[r0 + r][c2] = h;
    }
    __syncthreads();

    {
        const int row = t >> 3, q = t & 7;
        float s = 0.f;
        const float* hrow = &h2s[row][q * 8];
        const float* wrow = &mw3[q * 8];
#pragma unroll
        for (int kk = 0; kk < 8; ++kk) s += hrow[kk] * wrow[kk];
        s += __shfl_xor(s, 1);
        s += __shfl_xor(s, 2);
        s += __shfl_xor(s, 4);
        int b = b0 + row;
        if (q == 0 && b < B) out[b] = 1.0f / (1.0f + expf(-(s + mb3[0])));
    }
}

// ---------------------------------------------------------------------------
// launcher
// ---------------------------------------------------------------------------
extern "C" void kernel_launch(void* const* d_in, const int* in_sizes, int n_in,
                              void* d_out, int out_size, void* d_ws, size_t ws_size,
                              hipStream_t stream) {
    const int* uidx = (const int*)d_in[0];
    const int* vidx = (const int*)d_in[1];
    const int* eidx = (const int*)d_in[2];
    const float* utab = (const float*)d_in[3];
    const float* itab = (const float*)d_in[4];
    const float* W0 = (const float*)d_in[5];
    const float* as0 = (const float*)d_in[6];
    const float* ad0 = (const float*)d_in[7];
    const float* bb0 = (const float*)d_in[8];
    const float* W1 = (const float*)d_in[9];
    const float* as1 = (const float*)d_in[10];
    const float* ad1 = (const float*)d_in[11];
    const float* bb1 = (const float*)d_in[12];
    const float* W2 = (const float*)d_in[13];
    const float* as2 = (const float*)d_in[14];
    const float* ad2 = (const float*)d_in[15];
    const float* bb2 = (const float*)d_in[16];
    const float* ln_g = (const float*)d_in[17];
    const float* ln_b = (const float*)d_in[18];
    const float* mw1 = (const float*)d_in[19];
    const float* mb1 = (const float*)d_in[20];
    const float* mw2 = (const float*)d_in[21];
    const float* mb2 = (const float*)d_in[22];
    const float* mw3 = (const float*)d_in[23];
    const float* mb3 = (const float*)d_in[24];

    const int B = in_sizes[0];
    const int E = in_sizes[2] / 2;
    const int num_users = in_sizes[3] / D128;
    const int num_items = in_sizes[4] / D128;
    const int N = num_users + num_items;
    const int* esrc = eidx;
    const int* edst = eidx + E;

    size_t wsoff = 0;
    auto alloc = [&](size_t bytes) {
        void* p = (char*)d_ws + wsoff;
        wsoff += (bytes + 255) & ~(size_t)255;
        return p;
    };
    float* bufA = (float*)alloc((size_t)N * 128 * 4);
    float* bufB = (float*)alloc((size_t)N * 128 * 4);
    unsigned short* hb = (unsigned short*)alloc((size_t)N * 128 * 2);
    float* aS = (float*)alloc((size_t)N * 4 * 4);
    float* aD = (float*)alloc((size_t)N * 4 * 4);
    float* pbuf = (float*)alloc((size_t)E * 4 * 4);
    int* cnt = (int*)alloc((size_t)(N + 1) * 4);
    int* off = (int*)alloc((size_t)(N + 1) * 4);
    int* cur = (int*)alloc((size_t)(N + 1) * 4);
    int* csr_src = (int*)alloc((size_t)E * 4);
    int* csr_dst = (int*)alloc((size_t)E * 4);
    int* partials = (int*)alloc(64 * 4);
    int* pp = (int*)alloc(64 * 4);
    unsigned short* wb0 = (unsigned short*)alloc(2 * 16384 * 2);
    unsigned short* wb1 = (unsigned short*)alloc(2 * 16384 * 2);
    unsigned short* wb2 = (unsigned short*)alloc(2 * 16384 * 2);
    (void)ws_size;

    wrepack_kernel<<<64, 256, 0, stream>>>(W0, wb0);
    wrepack_kernel<<<64, 256, 0, stream>>>(W1, wb1);
    wrepack_kernel<<<64, 256, 0, stream>>>(W2, wb2);

    const int NB = (N + SCAN_CHUNK - 1) / SCAN_CHUNK;
    zero_int_kernel<<<(N + 255) / 256, 256, 0, stream>>>(cnt, N);
    count_kernel<<<(E + 255) / 256, 256, 0, stream>>>(edst, E, cnt);
    scan_local_kernel<<<NB, SB, 0, stream>>>(cnt, off, partials, N);
    scan_partials_kernel<<<1, 64, 0, stream>>>(partials, pp, NB, off, N);
    scan_add_kernel<<<(N + 255) / 256, 256, 0, stream>>>(off, cur, pp, N);
    fill_kernel<<<(E + 255) / 256, 256, 0, stream>>>(esrc, edst, E, cur, csr_src, csr_dst);

    const int gemm_grid = (N + 63) / 64;
    const int egrid = (E + 255) / 256;
    const int agrid = (N + 3) / 4;

    // ---- layer 0 (H=4, no residual; X = virtual concat of tables) ----
    gemm_mfma_kernel<4, true><<<gemm_grid, 256, 0, stream>>>(utab, itab, num_users, wb0, as0,
                                                             ad0, hb, aS, aD, N);
    pk4_kernel<<<egrid, 256, 0, stream>>>(csr_src, csr_dst, aS, aD, pbuf, E);
    agg_kernel<4, false><<<agrid, 256, 0, stream>>>(hb, pbuf, off, csr_src, nullptr, bb0, ln_g,
                                                    ln_b, bufB, N);
    // ---- layer 1 (H=4, residual) ----
    gemm_mfma_kernel<4, false><<<gemm_grid, 256, 0, stream>>>(bufB, nullptr, 0, wb1, as1, ad1,
                                                              hb, aS, aD, N);
    pk4_kernel<<<egrid, 256, 0, stream>>>(csr_src, csr_dst, aS, aD, pbuf, E);
    agg_kernel<4, true><<<agrid, 256, 0, stream>>>(hb, pbuf, off, csr_src, bufB, bb1, ln_g,
                                                   ln_b, bufA, N);
    // ---- layer 2 (H=1, residual) ----
    gemm_mfma_kernel<1, false><<<gemm_grid, 256, 0, stream>>>(bufA, nullptr, 0, wb2, as2, ad2,
                                                              hb, aS, aD, N);
    pk1_kernel<<<egrid, 256, 0, stream>>>(csr_src, csr_dst, aS, aD, pbuf, E);
    agg_kernel<1, true><<<agrid, 256, 0, stream>>>(hb, pbuf, off, csr_src, bufA, bb2, ln_g,
                                                   ln_b, bufB, N);

    // ---- prediction MLP ----
    mlp_kernel<<<(B + 31) / 32, 256, 0, stream>>>(bufB, uidx, vidx, num_users, mw1, mb1, mw2,
                                                  mb2, mw3, mb3, (float*)d_out, B);
}